// Round 3
// baseline (3363.654 us; speedup 1.0000x reference)
//
#include <hip/hip_runtime.h>
#include <hip/hip_bf16.h>

#define T_ 1024
#define D_ 1024
#define H_ 16
#define KV_ 4
#define DH_ 64
#define E_ 8
#define TOPK_ 2
#define F_ 512
#define FS_ 2048
#define L_ 2

// ---------------- embedding gather + zero residual ----------------
__global__ void k_embed(const int* __restrict__ ids, const float* __restrict__ emb,
                        float* __restrict__ h, float* __restrict__ res){
  int idx = blockIdx.x * 256 + threadIdx.x;   // T_*D_ total
  int t = idx >> 10, d = idx & 1023;
  h[idx] = emb[(size_t)ids[t] * D_ + d];
  res[idx] = 0.f;
}

// ---------------- elementwise ----------------
__global__ void k_add(float* __restrict__ dst, const float* __restrict__ src){
  int i = blockIdx.x * 256 + threadIdx.x;
  dst[i] += src[i];
}
__global__ void k_zero_f32(float* __restrict__ p){
  p[blockIdx.x * 256 + threadIdx.x] = 0.f;
}
__global__ void k_zero_i32(int* __restrict__ p, int n){
  int i = blockIdx.x * 64 + threadIdx.x;
  if (i < n) p[i] = 0;
}

// ---------------- RMSNorm over D (fp32 out) ----------------
__global__ __launch_bounds__(256)
void k_rms(const float* __restrict__ x, const float* __restrict__ w,
           float* __restrict__ out){
  int t = blockIdx.x, tid = threadIdx.x;
  const float* xr = x + (size_t)t * D_;
  float ss = 0.f;
  for (int d = tid; d < D_; d += 256){ float v = xr[d]; ss += v * v; }
  #pragma unroll
  for (int o = 32; o; o >>= 1) ss += __shfl_xor(ss, o);
  __shared__ float red[4];
  if ((tid & 63) == 0) red[tid >> 6] = ss;
  __syncthreads();
  float r = rsqrtf((red[0] + red[1] + red[2] + red[3]) * (1.f / D_) + 1e-6f);
  float* orow = out + (size_t)t * D_;
  for (int d = tid; d < D_; d += 256) orow[d] = xr[d] * r * w[d];
}

// ---------------- per-head RMSNorm + RoPE (in place) ----------------
__global__ __launch_bounds__(64)
void k_qknorm_rope(float* __restrict__ buf, const float* __restrict__ nw,
                   const int* __restrict__ pos, int nheads){
  int row = blockIdx.x;          // t*nheads + head
  int t = row / nheads;
  int lane = threadIdx.x;        // 64
  int base = row * DH_ + lane;
  float x = buf[base];
  float ss = x * x;
  #pragma unroll
  for (int o = 32; o; o >>= 1) ss += __shfl_xor(ss, o);
  float r = rsqrtf(ss * (1.f / DH_) + 1e-6f);
  float xn = x * r * nw[lane];
  int j = lane & 31;
  float inv = powf(1.0e6f, -(float)j * (1.f / 32.f));
  float ang = (float)pos[t] * inv;
  float s, c;
  sincosf(ang, &s, &c);
  float p = __shfl_xor(xn, 32);
  float rot = (lane < 32) ? -p : p;
  buf[base] = xn * c + rot * s;
}

// ---------------- attention: one (head, query) per block ----------------
__global__ __launch_bounds__(256)
void k_attn(const float* __restrict__ q, const float* __restrict__ k,
            const float* __restrict__ v, float* __restrict__ out){
  int h = blockIdx.x, t = blockIdx.y;
  int kv = h >> 2;
  int tid = threadIdx.x;
  __shared__ float qs[DH_];
  __shared__ float sc[T_];
  __shared__ float red[8];
  __shared__ float pv[4][DH_];
  if (tid < DH_) qs[tid] = q[((size_t)t * H_ + h) * DH_ + tid];
  __syncthreads();
  int nk = t + 1;
  float mx = -1e30f;
  for (int jj = tid; jj < nk; jj += 256){
    const float* kp = k + ((size_t)jj * KV_ + kv) * DH_;
    float s = 0.f;
    #pragma unroll
    for (int d = 0; d < DH_; d++) s += qs[d] * kp[d];
    s *= 0.125f;
    sc[jj] = s;
    mx = fmaxf(mx, s);
  }
  #pragma unroll
  for (int o = 32; o; o >>= 1) mx = fmaxf(mx, __shfl_xor(mx, o));
  if ((tid & 63) == 0) red[tid >> 6] = mx;
  __syncthreads();
  mx = fmaxf(fmaxf(red[0], red[1]), fmaxf(red[2], red[3]));
  float ls = 0.f;
  for (int jj = tid; jj < nk; jj += 256){
    float p = __expf(sc[jj] - mx);
    sc[jj] = p;
    ls += p;
  }
  #pragma unroll
  for (int o = 32; o; o >>= 1) ls += __shfl_xor(ls, o);
  if ((tid & 63) == 0) red[4 + (tid >> 6)] = ls;
  __syncthreads();
  float den = red[4] + red[5] + red[6] + red[7];
  int d = tid & 63, g = tid >> 6;
  float acc = 0.f;
  for (int jj = g; jj < nk; jj += 4) acc += sc[jj] * v[((size_t)jj * KV_ + kv) * DH_ + d];
  pv[g][d] = acc;
  __syncthreads();
  if (g == 0){
    out[(size_t)t * (H_ * DH_) + h * DH_ + d] = (pv[0][d] + pv[1][d] + pv[2][d] + pv[3][d]) / den;
  }
}

// ---------------- tiled GEMM: C[M,N] = A[M,K](f32) @ B[K,N](f32) ----------------
__global__ __launch_bounds__(256)
void k_gemm(const float* __restrict__ A, const float* __restrict__ B,
            float* __restrict__ C, int M, int N, int K){
  __shared__ float As[16][65];
  __shared__ float Bs[16][65];
  int tid = threadIdx.x;
  int tx = tid & 15, ty = tid >> 4;
  int row0 = blockIdx.y * 64, col0 = blockIdx.x * 64;
  int a_m = tid >> 2, a_k = (tid & 3) * 4;
  int b_k = tid >> 4, b_n = (tid & 15) * 4;
  float acc[4][4] = {};
  int gm = row0 + a_m;
  bool aok = gm < M;
  const float* Ap = A + (size_t)gm * K + a_k;
  const float* Bp = B + (size_t)b_k * N + col0 + b_n;
  for (int k0 = 0; k0 < K; k0 += 16){
    float4 av = aok ? *(const float4*)(Ap + k0) : make_float4(0.f, 0.f, 0.f, 0.f);
    As[a_k + 0][a_m] = av.x;
    As[a_k + 1][a_m] = av.y;
    As[a_k + 2][a_m] = av.z;
    As[a_k + 3][a_m] = av.w;
    float4 bv = *(const float4*)(Bp + (size_t)k0 * N);
    Bs[b_k][b_n + 0] = bv.x;
    Bs[b_k][b_n + 1] = bv.y;
    Bs[b_k][b_n + 2] = bv.z;
    Bs[b_k][b_n + 3] = bv.w;
    __syncthreads();
    #pragma unroll
    for (int kk = 0; kk < 16; kk++){
      float a0 = As[kk][ty * 4 + 0], a1 = As[kk][ty * 4 + 1],
            a2 = As[kk][ty * 4 + 2], a3 = As[kk][ty * 4 + 3];
      float b0 = Bs[kk][tx * 4 + 0], b1 = Bs[kk][tx * 4 + 1],
            b2 = Bs[kk][tx * 4 + 2], b3 = Bs[kk][tx * 4 + 3];
      acc[0][0] += a0 * b0; acc[0][1] += a0 * b1; acc[0][2] += a0 * b2; acc[0][3] += a0 * b3;
      acc[1][0] += a1 * b0; acc[1][1] += a1 * b1; acc[1][2] += a1 * b2; acc[1][3] += a1 * b3;
      acc[2][0] += a2 * b0; acc[2][1] += a2 * b1; acc[2][2] += a2 * b2; acc[2][3] += a2 * b3;
      acc[3][0] += a3 * b0; acc[3][1] += a3 * b1; acc[3][2] += a3 * b2; acc[3][3] += a3 * b3;
    }
    __syncthreads();
  }
  #pragma unroll
  for (int i = 0; i < 4; i++){
    int r = row0 + ty * 4 + i;
    if (r < M){
      float* cp = C + (size_t)r * N + col0 + tx * 4;
      cp[0] = acc[i][0]; cp[1] = acc[i][1]; cp[2] = acc[i][2]; cp[3] = acc[i][3];
    }
  }
}

// ---------------- expert up GEMM (gathered rows): G[off+r] = hn[tok[r]] @ egu[e] ----------------
__global__ __launch_bounds__(256)
void k_gemm_up(const float* __restrict__ hn, const float* __restrict__ egu_l,
               float* __restrict__ G, const int* __restrict__ counts,
               const int* __restrict__ offsets, const int* __restrict__ rowtok){
  const int e = blockIdx.z;
  const int me = counts[e];
  const int row0 = blockIdx.y * 64;
  if (row0 >= me) return;
  const int off = offsets[e];
  const float* B = egu_l + (size_t)e * D_ * (2 * F_);
  const int N = 2 * F_;   // 1024
  const int K = D_;
  __shared__ float As[16][65];
  __shared__ float Bs[16][65];
  int tid = threadIdx.x;
  int tx = tid & 15, ty = tid >> 4;
  int col0 = blockIdx.x * 64;
  int a_m = tid >> 2, a_k = (tid & 3) * 4;
  int b_k = tid >> 4, b_n = (tid & 15) * 4;
  float acc[4][4] = {};
  int gm = row0 + a_m;
  bool aok = gm < me;
  const float* Ap = aok ? (hn + (size_t)rowtok[off + gm] * D_ + a_k) : hn;
  const float* Bp = B + (size_t)b_k * N + col0 + b_n;
  for (int k0 = 0; k0 < K; k0 += 16){
    float4 av = aok ? *(const float4*)(Ap + k0) : make_float4(0.f, 0.f, 0.f, 0.f);
    As[a_k + 0][a_m] = av.x;
    As[a_k + 1][a_m] = av.y;
    As[a_k + 2][a_m] = av.z;
    As[a_k + 3][a_m] = av.w;
    float4 bv = *(const float4*)(Bp + (size_t)k0 * N);
    Bs[b_k][b_n + 0] = bv.x;
    Bs[b_k][b_n + 1] = bv.y;
    Bs[b_k][b_n + 2] = bv.z;
    Bs[b_k][b_n + 3] = bv.w;
    __syncthreads();
    #pragma unroll
    for (int kk = 0; kk < 16; kk++){
      float a0 = As[kk][ty * 4 + 0], a1 = As[kk][ty * 4 + 1],
            a2 = As[kk][ty * 4 + 2], a3 = As[kk][ty * 4 + 3];
      float b0 = Bs[kk][tx * 4 + 0], b1 = Bs[kk][tx * 4 + 1],
            b2 = Bs[kk][tx * 4 + 2], b3 = Bs[kk][tx * 4 + 3];
      acc[0][0] += a0 * b0; acc[0][1] += a0 * b1; acc[0][2] += a0 * b2; acc[0][3] += a0 * b3;
      acc[1][0] += a1 * b0; acc[1][1] += a1 * b1; acc[1][2] += a1 * b2; acc[1][3] += a1 * b3;
      acc[2][0] += a2 * b0; acc[2][1] += a2 * b1; acc[2][2] += a2 * b2; acc[2][3] += a2 * b3;
      acc[3][0] += a3 * b0; acc[3][1] += a3 * b1; acc[3][2] += a3 * b2; acc[3][3] += a3 * b3;
    }
    __syncthreads();
  }
  #pragma unroll
  for (int i = 0; i < 4; i++){
    int r = row0 + ty * 4 + i;
    if (r < me){
      float* cp = G + (size_t)(off + r) * N + col0 + tx * 4;
      cp[0] = acc[i][0]; cp[1] = acc[i][1]; cp[2] = acc[i][2]; cp[3] = acc[i][3];
    }
  }
}

// ---------------- expert down GEMM + weighted scatter-add ----------------
__global__ __launch_bounds__(256)
void k_gemm_dn(const float* __restrict__ he, const float* __restrict__ edn_l,
               float* __restrict__ routed, const int* __restrict__ counts,
               const int* __restrict__ offsets, const int* __restrict__ rowtok,
               const float* __restrict__ roww){
  const int e = blockIdx.z;
  const int me = counts[e];
  const int row0 = blockIdx.y * 64;
  if (row0 >= me) return;
  const int off = offsets[e];
  const float* B = edn_l + (size_t)e * F_ * D_;
  const int N = D_;
  const int K = F_;   // 512
  __shared__ float As[16][65];
  __shared__ float Bs[16][65];
  int tid = threadIdx.x;
  int tx = tid & 15, ty = tid >> 4;
  int col0 = blockIdx.x * 64;
  int a_m = tid >> 2, a_k = (tid & 3) * 4;
  int b_k = tid >> 4, b_n = (tid & 15) * 4;
  float acc[4][4] = {};
  int gm = row0 + a_m;
  bool aok = gm < me;
  const float* Ap = he + (size_t)(off + (aok ? gm : 0)) * F_ + a_k;
  const float* Bp = B + (size_t)b_k * N + col0 + b_n;
  for (int k0 = 0; k0 < K; k0 += 16){
    float4 av = aok ? *(const float4*)(Ap + k0) : make_float4(0.f, 0.f, 0.f, 0.f);
    As[a_k + 0][a_m] = av.x;
    As[a_k + 1][a_m] = av.y;
    As[a_k + 2][a_m] = av.z;
    As[a_k + 3][a_m] = av.w;
    float4 bv = *(const float4*)(Bp + (size_t)k0 * N);
    Bs[b_k][b_n + 0] = bv.x;
    Bs[b_k][b_n + 1] = bv.y;
    Bs[b_k][b_n + 2] = bv.z;
    Bs[b_k][b_n + 3] = bv.w;
    __syncthreads();
    #pragma unroll
    for (int kk = 0; kk < 16; kk++){
      float a0 = As[kk][ty * 4 + 0], a1 = As[kk][ty * 4 + 1],
            a2 = As[kk][ty * 4 + 2], a3 = As[kk][ty * 4 + 3];
      float b0 = Bs[kk][tx * 4 + 0], b1 = Bs[kk][tx * 4 + 1],
            b2 = Bs[kk][tx * 4 + 2], b3 = Bs[kk][tx * 4 + 3];
      acc[0][0] += a0 * b0; acc[0][1] += a0 * b1; acc[0][2] += a0 * b2; acc[0][3] += a0 * b3;
      acc[1][0] += a1 * b0; acc[1][1] += a1 * b1; acc[1][2] += a1 * b2; acc[1][3] += a1 * b3;
      acc[2][0] += a2 * b0; acc[2][1] += a2 * b1; acc[2][2] += a2 * b2; acc[2][3] += a2 * b3;
      acc[3][0] += a3 * b0; acc[3][1] += a3 * b1; acc[3][2] += a3 * b2; acc[3][3] += a3 * b3;
    }
    __syncthreads();
  }
  #pragma unroll
  for (int i = 0; i < 4; i++){
    int r = row0 + ty * 4 + i;
    if (r < me){
      int tok = rowtok[off + r];
      float w = roww[off + r];
      float* cp = routed + (size_t)tok * D_ + col0 + tx * 4;
      atomicAdd(&cp[0], w * acc[i][0]);
      atomicAdd(&cp[1], w * acc[i][1]);
      atomicAdd(&cp[2], w * acc[i][2]);
      atomicAdd(&cp[3], w * acc[i][3]);
    }
  }
}

// ---------------- SiLU(gate)*up:  g rows [width] -> out rows [half] ----------------
__global__ void k_silumul(const float* __restrict__ g, float* __restrict__ out,
                          int width, int half){
  int idx = blockIdx.x * 256 + threadIdx.x;
  int r = idx / half, f = idx - r * half;
  float a = g[(size_t)r * width + f];
  float b = g[(size_t)r * width + half + f];
  out[idx] = a * b / (1.f + __expf(-a));
}

// ---------------- shared-expert sigmoid gate ----------------
__global__ __launch_bounds__(256)
void k_gate(const float* __restrict__ hn, const float* __restrict__ sg,
            float* __restrict__ gate){
  int t = blockIdx.x, tid = threadIdx.x;
  const float* xr = hn + (size_t)t * D_;
  float s = 0.f;
  for (int d = tid; d < D_; d += 256) s += xr[d] * sg[d];
  #pragma unroll
  for (int o = 32; o; o >>= 1) s += __shfl_xor(s, o);
  __shared__ float red[4];
  if ((tid & 63) == 0) red[tid >> 6] = s;
  __syncthreads();
  if (tid == 0){
    float tot = red[0] + red[1] + red[2] + red[3];
    gate[t] = 1.f / (1.f + __expf(-tot));
  }
}

// ---------------- router: softmax + top-2 + renorm, count experts ----------------
__global__ __launch_bounds__(64)
void k_router(const float* __restrict__ hn, const float* __restrict__ rw,
              int* __restrict__ counts, int* __restrict__ top_e,
              float* __restrict__ top_w){
  int t = blockIdx.x;
  int lane = threadIdx.x;       // 64
  int e = lane & 7, c = lane >> 3;
  const float* xr = hn + (size_t)t * D_;
  float s = 0.f;
  for (int d = c * 128; d < c * 128 + 128; d++) s += xr[d] * rw[d * E_ + e];
  s += __shfl_down(s, 32);
  s += __shfl_down(s, 16);
  s += __shfl_down(s, 8);
  float v[8];
  #pragma unroll
  for (int qq = 0; qq < 8; qq++) v[qq] = __shfl(s, qq);
  if (lane == 0){
    float mx = v[0];
    #pragma unroll
    for (int qq = 1; qq < 8; qq++) mx = fmaxf(mx, v[qq]);
    float p[8];
    #pragma unroll
    for (int qq = 0; qq < 8; qq++) p[qq] = __expf(v[qq] - mx);
    int i0 = 0;
    #pragma unroll
    for (int qq = 1; qq < 8; qq++) if (p[qq] > p[i0]) i0 = qq;
    int i1 = (i0 == 0) ? 1 : 0;
    #pragma unroll
    for (int qq = 0; qq < 8; qq++) if (qq != i0 && p[qq] > p[i1]) i1 = qq;
    float w0 = p[i0], w1 = p[i1];
    float inv = 1.f / (w0 + w1);
    top_e[t * 2 + 0] = i0; top_w[t * 2 + 0] = w0 * inv;
    top_e[t * 2 + 1] = i1; top_w[t * 2 + 1] = w1 * inv;
    atomicAdd(&counts[i0], 1);
    atomicAdd(&counts[i1], 1);
  }
}

__global__ void k_prefix(const int* __restrict__ counts, int* __restrict__ offsets,
                         int* __restrict__ cursor){
  if (threadIdx.x == 0 && blockIdx.x == 0){
    int acc = 0;
    for (int e = 0; e < E_; e++){ offsets[e] = acc; cursor[e] = acc; acc += counts[e]; }
  }
}

__global__ void k_assign(const int* __restrict__ top_e, const float* __restrict__ top_w,
                         int* __restrict__ cursor, int* __restrict__ rowtok,
                         float* __restrict__ roww){
  int i = blockIdx.x * 256 + threadIdx.x;   // 2048 total
  if (i >= T_ * TOPK_) return;
  int e = top_e[i];
  int slot = atomicAdd(&cursor[e], 1);
  rowtok[slot] = i >> 1;
  roww[slot] = top_w[i];
}

// ---------------- h = routed + shared * gate[t] ----------------
__global__ void k_combine(float* __restrict__ h, const float* __restrict__ routed,
                          const float* __restrict__ shexp, const float* __restrict__ gate){
  int idx = blockIdx.x * 256 + threadIdx.x;
  h[idx] = routed[idx] + shexp[idx] * gate[idx >> 10];
}

// ---------------- final: out = rms(res + h, final_ln), fp32 out ----------------
__global__ __launch_bounds__(256)
void k_final_rms(const float* __restrict__ resv, const float* __restrict__ hv,
                 const float* __restrict__ w, float* __restrict__ out){
  int t = blockIdx.x, tid = threadIdx.x;
  const float* xr = resv + (size_t)t * D_;
  const float* hr = hv + (size_t)t * D_;
  float ss = 0.f;
  for (int d = tid; d < D_; d += 256){ float v = xr[d] + hr[d]; ss += v * v; }
  #pragma unroll
  for (int o = 32; o; o >>= 1) ss += __shfl_xor(ss, o);
  __shared__ float red[4];
  if ((tid & 63) == 0) red[tid >> 6] = ss;
  __syncthreads();
  float r = rsqrtf((red[0] + red[1] + red[2] + red[3]) * (1.f / D_) + 1e-6f);
  float* orow = out + (size_t)t * D_;
  for (int d = tid; d < D_; d += 256) orow[d] = (xr[d] + hr[d]) * r * w[d];
}

extern "C" void kernel_launch(void* const* d_in, const int* in_sizes, int n_in,
                              void* d_out, int out_size, void* d_ws, size_t ws_size,
                              hipStream_t stream){
  (void)in_sizes; (void)n_in; (void)out_size; (void)ws_size;
  const int* ids = (const int*)d_in[0];
  const int* pos = (const int*)d_in[1];
  const float* emb = (const float*)d_in[2];
  const float* ln1 = (const float*)d_in[3];
  const float* wq  = (const float*)d_in[4];
  const float* wk  = (const float*)d_in[5];
  const float* wv  = (const float*)d_in[6];
  const float* wo  = (const float*)d_in[7];
  const float* qn  = (const float*)d_in[8];
  const float* kn  = (const float*)d_in[9];
  const float* ln2 = (const float*)d_in[10];
  const float* rw  = (const float*)d_in[11];
  const float* egu = (const float*)d_in[12];
  const float* edn = (const float*)d_in[13];
  const float* sgu = (const float*)d_in[14];
  const float* sdn = (const float*)d_in[15];
  const float* sg  = (const float*)d_in[16];
  const float* fln = (const float*)d_in[17];

  float* ws = (float*)d_ws;
  const size_t MB = (size_t)1 << 20;   // 1M floats
  float* res    = ws;
  float* h      = ws + 1 * MB;
  float* hn     = ws + 2 * MB;
  float* qlin   = ws + 3 * MB;
  float* kbuf   = ws + 4 * MB;                 // 256K
  float* vbuf   = kbuf + T_ * KV_ * DH_;       // 256K
  float* attnb  = ws + 5 * MB;
  float* gu     = ws + 6 * MB;                 // 4M
  float* sact   = ws + 10 * MB;                // 2M
  float* shexp  = ws + 12 * MB;
  float* G      = ws + 13 * MB;                // 2M
  float* he     = ws + 15 * MB;
  float* routed = ws + 16 * MB;
  float* gate   = ws + 17 * MB;                // 1K
  float* roww   = gate + 4096;
  float* top_w  = roww + 4096;
  int* counts   = (int*)(top_w + 4096);
  int* offsets  = counts + 8;
  int* cursor   = offsets + 8;
  int* top_e    = cursor + 8;                  // 2048
  int* rowtok   = top_e + 2048;                // 2048

  const int NTD = T_ * D_ / 256;   // 4096 blocks for [T,D] elementwise

  k_embed<<<NTD, 256, 0, stream>>>(ids, emb, h, res);

  for (int i = 0; i < L_; i++){
    // ---- attention ----
    k_add<<<NTD, 256, 0, stream>>>(res, h);
    k_rms<<<T_, 256, 0, stream>>>(res, ln1 + (size_t)i * D_, hn);
    k_gemm<<<dim3(16, 16), 256, 0, stream>>>(hn, wq + (size_t)i * D_ * (H_ * DH_), qlin, T_, H_ * DH_, D_);
    k_gemm<<<dim3(4, 16), 256, 0, stream>>>(hn, wk + (size_t)i * D_ * (KV_ * DH_), kbuf, T_, KV_ * DH_, D_);
    k_gemm<<<dim3(4, 16), 256, 0, stream>>>(hn, wv + (size_t)i * D_ * (KV_ * DH_), vbuf, T_, KV_ * DH_, D_);
    k_qknorm_rope<<<T_ * H_, 64, 0, stream>>>(qlin, qn + (size_t)i * DH_, pos, H_);
    k_qknorm_rope<<<T_ * KV_, 64, 0, stream>>>(kbuf, kn + (size_t)i * DH_, pos, KV_);
    k_attn<<<dim3(H_, T_), 256, 0, stream>>>(qlin, kbuf, vbuf, attnb);
    k_gemm<<<dim3(16, 16), 256, 0, stream>>>(attnb, wo + (size_t)i * (H_ * DH_) * D_, h, T_, D_, H_ * DH_);
    k_add<<<NTD, 256, 0, stream>>>(res, h);
    // ---- MoE MLP ----
    k_rms<<<T_, 256, 0, stream>>>(res, ln2 + (size_t)i * D_, hn);
    // shared expert
    k_gemm<<<dim3(64, 16), 256, 0, stream>>>(hn, sgu + (size_t)i * D_ * (2 * FS_), gu, T_, 2 * FS_, D_);
    k_silumul<<<T_ * FS_ / 256, 256, 0, stream>>>(gu, sact, 2 * FS_, FS_);
    k_gemm<<<dim3(16, 16), 256, 0, stream>>>(sact, sdn + (size_t)i * FS_ * D_, shexp, T_, D_, FS_);
    k_gate<<<T_, 256, 0, stream>>>(hn, sg + (size_t)i * D_, gate);
    // routed experts
    k_zero_i32<<<1, 64, 0, stream>>>(counts, 8);
    k_router<<<T_, 64, 0, stream>>>(hn, rw + (size_t)i * D_ * E_, counts, top_e, top_w);
    k_prefix<<<1, 1, 0, stream>>>(counts, offsets, cursor);
    k_assign<<<8, 256, 0, stream>>>(top_e, top_w, cursor, rowtok, roww);
    k_gemm_up<<<dim3(16, 32, 8), 256, 0, stream>>>(hn, egu + (size_t)i * E_ * D_ * (2 * F_), G, counts, offsets, rowtok);
    k_silumul<<<T_ * TOPK_ * F_ / 256, 256, 0, stream>>>(G, he, 2 * F_, F_);
    k_zero_f32<<<NTD, 256, 0, stream>>>(routed);
    k_gemm_dn<<<dim3(16, 32, 8), 256, 0, stream>>>(he, edn + (size_t)i * E_ * F_ * D_, routed, counts, offsets, rowtok, roww);
    k_combine<<<NTD, 256, 0, stream>>>(h, routed, shexp, gate);
  }

  k_final_rms<<<T_, 256, 0, stream>>>(res, h, fln, (float*)d_out);
}

// Round 5
// 2497.769 us; speedup vs baseline: 1.3467x; 1.3467x over previous
//
#include <hip/hip_runtime.h>
#include <hip/hip_bf16.h>

#define T_ 1024
#define D_ 1024
#define H_ 16
#define KV_ 4
#define DH_ 64
#define E_ 8
#define TOPK_ 2
#define F_ 512
#define FS_ 2048
#define L_ 2

typedef unsigned int uint32;
typedef __attribute__((ext_vector_type(8))) short short8;
typedef __attribute__((ext_vector_type(4))) float f32x4;

__device__ __forceinline__ short f2bf(float f){   // RNE fp32 -> bf16 bits
  uint32 u = __float_as_uint(f);
  return (short)((u + 0x7fffu + ((u >> 16) & 1u)) >> 16);
}
__device__ __forceinline__ float bf2f(short s){
  return __uint_as_float(((uint32)(unsigned short)s) << 16);
}
__device__ __forceinline__ void split2(float x, short& hi, short& lo){
  hi = f2bf(x);
  lo = f2bf(x - bf2f(hi));
}

// ---------------- embedding gather + zero residual ----------------
__global__ void k_embed(const int* __restrict__ ids, const float* __restrict__ emb,
                        float* __restrict__ h, float* __restrict__ res){
  int idx = blockIdx.x * 256 + threadIdx.x;
  int t = idx >> 10, d = idx & 1023;
  h[idx] = emb[(size_t)ids[t] * D_ + d];
  res[idx] = 0.f;
}

// ---------------- elementwise ----------------
__global__ void k_add(float* __restrict__ dst, const float* __restrict__ src){
  int i = blockIdx.x * 256 + threadIdx.x;
  dst[i] += src[i];
}
__global__ void k_zero_f32(float* __restrict__ p){
  p[blockIdx.x * 256 + threadIdx.x] = 0.f;
}
__global__ void k_zero_i32(int* __restrict__ p, int n){
  int i = blockIdx.x * 64 + threadIdx.x;
  if (i < n) p[i] = 0;
}

// ---------------- RMSNorm over D (fp32 out) ----------------
__global__ __launch_bounds__(256)
void k_rms(const float* __restrict__ x, const float* __restrict__ w,
           float* __restrict__ out){
  int t = blockIdx.x, tid = threadIdx.x;
  const float* xr = x + (size_t)t * D_;
  float ss = 0.f;
  for (int d = tid; d < D_; d += 256){ float v = xr[d]; ss += v * v; }
  #pragma unroll
  for (int o = 32; o; o >>= 1) ss += __shfl_xor(ss, o);
  __shared__ float red[4];
  if ((tid & 63) == 0) red[tid >> 6] = ss;
  __syncthreads();
  float r = rsqrtf((red[0] + red[1] + red[2] + red[3]) * (1.f / D_) + 1e-6f);
  float* orow = out + (size_t)t * D_;
  for (int d = tid; d < D_; d += 256) orow[d] = xr[d] * r * w[d];
}

// ---------------- per-head RMSNorm + RoPE (in place) ----------------
__global__ __launch_bounds__(64)
void k_qknorm_rope(float* __restrict__ buf, const float* __restrict__ nw,
                   const int* __restrict__ pos, int nheads){
  int row = blockIdx.x;
  int t = row / nheads;
  int lane = threadIdx.x;
  int base = row * DH_ + lane;
  float x = buf[base];
  float ss = x * x;
  #pragma unroll
  for (int o = 32; o; o >>= 1) ss += __shfl_xor(ss, o);
  float r = rsqrtf(ss * (1.f / DH_) + 1e-6f);
  float xn = x * r * nw[lane];
  int j = lane & 31;
  float inv = powf(1.0e6f, -(float)j * (1.f / 32.f));
  float ang = (float)pos[t] * inv;
  float s, c;
  sincosf(ang, &s, &c);
  float p = __shfl_xor(xn, 32);
  float rot = (lane < 32) ? -p : p;
  buf[base] = xn * c + rot * s;
}

// ---------------- attention: one (head, query) per block (known-good r3) ----------------
__global__ __launch_bounds__(256)
void k_attn(const float* __restrict__ q, const float* __restrict__ k,
            const float* __restrict__ v, float* __restrict__ out){
  int h = blockIdx.x, t = blockIdx.y;
  int kv = h >> 2;
  int tid = threadIdx.x;
  __shared__ float qs[DH_];
  __shared__ float sc[T_];
  __shared__ float red[8];
  __shared__ float pv[4][DH_];
  if (tid < DH_) qs[tid] = q[((size_t)t * H_ + h) * DH_ + tid];
  __syncthreads();
  int nk = t + 1;
  float mx = -1e30f;
  for (int jj = tid; jj < nk; jj += 256){
    const float* kp = k + ((size_t)jj * KV_ + kv) * DH_;
    float s = 0.f;
    #pragma unroll
    for (int d = 0; d < DH_; d++) s += qs[d] * kp[d];
    s *= 0.125f;
    sc[jj] = s;
    mx = fmaxf(mx, s);
  }
  #pragma unroll
  for (int o = 32; o; o >>= 1) mx = fmaxf(mx, __shfl_xor(mx, o));
  if ((tid & 63) == 0) red[tid >> 6] = mx;
  __syncthreads();
  mx = fmaxf(fmaxf(red[0], red[1]), fmaxf(red[2], red[3]));
  float ls = 0.f;
  for (int jj = tid; jj < nk; jj += 256){
    float p = __expf(sc[jj] - mx);
    sc[jj] = p;
    ls += p;
  }
  #pragma unroll
  for (int o = 32; o; o >>= 1) ls += __shfl_xor(ls, o);
  if ((tid & 63) == 0) red[4 + (tid >> 6)] = ls;
  __syncthreads();
  float den = red[4] + red[5] + red[6] + red[7];
  int d = tid & 63, g = tid >> 6;
  float acc = 0.f;
  for (int jj = g; jj < nk; jj += 4) acc += sc[jj] * v[((size_t)jj * KV_ + kv) * DH_ + d];
  pv[g][d] = acc;
  __syncthreads();
  if (g == 0){
    out[(size_t)t * (H_ * DH_) + h * DH_ + d] = (pv[0][d] + pv[1][d] + pv[2][d] + pv[3][d]) / den;
  }
}

// ---------------- split-bf16 MFMA GEMM: C = A @ B, ~fp32 accuracy ----------------
__global__ __launch_bounds__(256)
void k_mgemm(const float* __restrict__ A, const float* __restrict__ B,
             float* __restrict__ C, int M, int N, int K){
  __shared__ short Ah[64][40], Al[64][40];
  __shared__ short Bh[64][40], Bl[64][40];
  int tid = threadIdx.x;
  int row0 = blockIdx.y * 64, col0 = blockIdx.x * 64;
  int w = tid >> 6, lane = tid & 63, l16 = lane & 15, lq = lane >> 4;
  f32x4 acc[4] = {};
  int ar = tid >> 3, ak = (tid & 7) * 4;
  int bk = tid >> 4, bn = (tid & 15) * 4;
  for (int k0 = 0; k0 < K; k0 += 32){
    #pragma unroll
    for (int rr = 0; rr < 64; rr += 32){
      int r = ar + rr, grow = row0 + r;
      float4 av = (grow < M) ? *(const float4*)(A + (size_t)grow * K + k0 + ak)
                             : make_float4(0.f, 0.f, 0.f, 0.f);
      split2(av.x, Ah[r][ak + 0], Al[r][ak + 0]);
      split2(av.y, Ah[r][ak + 1], Al[r][ak + 1]);
      split2(av.z, Ah[r][ak + 2], Al[r][ak + 2]);
      split2(av.w, Ah[r][ak + 3], Al[r][ak + 3]);
    }
    #pragma unroll
    for (int kk = 0; kk < 32; kk += 16){
      int kb = bk + kk;
      float4 bv = *(const float4*)(B + (size_t)(k0 + kb) * N + col0 + bn);
      split2(bv.x, Bh[bn + 0][kb], Bl[bn + 0][kb]);
      split2(bv.y, Bh[bn + 1][kb], Bl[bn + 1][kb]);
      split2(bv.z, Bh[bn + 2][kb], Bl[bn + 2][kb]);
      split2(bv.w, Bh[bn + 3][kb], Bl[bn + 3][kb]);
    }
    __syncthreads();
    short8 ah = *(const short8*)&Ah[w * 16 + l16][lq * 8];
    short8 al = *(const short8*)&Al[w * 16 + l16][lq * 8];
    #pragma unroll
    for (int nt = 0; nt < 4; nt++){
      short8 bh = *(const short8*)&Bh[nt * 16 + l16][lq * 8];
      short8 bl = *(const short8*)&Bl[nt * 16 + l16][lq * 8];
      acc[nt] = __builtin_amdgcn_mfma_f32_16x16x32_bf16(ah, bh, acc[nt], 0, 0, 0);
      acc[nt] = __builtin_amdgcn_mfma_f32_16x16x32_bf16(ah, bl, acc[nt], 0, 0, 0);
      acc[nt] = __builtin_amdgcn_mfma_f32_16x16x32_bf16(al, bh, acc[nt], 0, 0, 0);
    }
    __syncthreads();
  }
  #pragma unroll
  for (int nt = 0; nt < 4; nt++)
    #pragma unroll
    for (int i = 0; i < 4; i++){
      int r = row0 + w * 16 + lq * 4 + i;
      if (r < M) C[(size_t)r * N + col0 + nt * 16 + l16] = acc[nt][i];
    }
}

// ---------------- expert up split-bf16 MFMA GEMM (gathered A rows) ----------------
__global__ __launch_bounds__(256)
void k_mgemm_up(const float* __restrict__ hn, const float* __restrict__ egu_l,
                float* __restrict__ G, const int* __restrict__ counts,
                const int* __restrict__ offsets, const int* __restrict__ rowtok){
  const int e = blockIdx.z;
  const int me = counts[e];
  const int row0 = blockIdx.y * 64;
  if (row0 >= me) return;
  const int off = offsets[e];
  const float* B = egu_l + (size_t)e * D_ * (2 * F_);
  const int N = 2 * F_, K = D_;
  __shared__ short Ah[64][40], Al[64][40];
  __shared__ short Bh[64][40], Bl[64][40];
  int tid = threadIdx.x;
  int col0 = blockIdx.x * 64;
  int w = tid >> 6, lane = tid & 63, l16 = lane & 15, lq = lane >> 4;
  f32x4 acc[4] = {};
  int ar = tid >> 3, ak = (tid & 7) * 4;
  int bk = tid >> 4, bn = (tid & 15) * 4;
  int tok0 = (row0 + ar      < me) ? rowtok[off + row0 + ar]      : -1;
  int tok1 = (row0 + ar + 32 < me) ? rowtok[off + row0 + ar + 32] : -1;
  for (int k0 = 0; k0 < K; k0 += 32){
    {
      float4 av = (tok0 >= 0) ? *(const float4*)(hn + (size_t)tok0 * D_ + k0 + ak)
                              : make_float4(0.f, 0.f, 0.f, 0.f);
      split2(av.x, Ah[ar][ak + 0], Al[ar][ak + 0]);
      split2(av.y, Ah[ar][ak + 1], Al[ar][ak + 1]);
      split2(av.z, Ah[ar][ak + 2], Al[ar][ak + 2]);
      split2(av.w, Ah[ar][ak + 3], Al[ar][ak + 3]);
      float4 aw = (tok1 >= 0) ? *(const float4*)(hn + (size_t)tok1 * D_ + k0 + ak)
                              : make_float4(0.f, 0.f, 0.f, 0.f);
      split2(aw.x, Ah[ar + 32][ak + 0], Al[ar + 32][ak + 0]);
      split2(aw.y, Ah[ar + 32][ak + 1], Al[ar + 32][ak + 1]);
      split2(aw.z, Ah[ar + 32][ak + 2], Al[ar + 32][ak + 2]);
      split2(aw.w, Ah[ar + 32][ak + 3], Al[ar + 32][ak + 3]);
    }
    #pragma unroll
    for (int kk = 0; kk < 32; kk += 16){
      int kb = bk + kk;
      float4 bv = *(const float4*)(B + (size_t)(k0 + kb) * N + col0 + bn);
      split2(bv.x, Bh[bn + 0][kb], Bl[bn + 0][kb]);
      split2(bv.y, Bh[bn + 1][kb], Bl[bn + 1][kb]);
      split2(bv.z, Bh[bn + 2][kb], Bl[bn + 2][kb]);
      split2(bv.w, Bh[bn + 3][kb], Bl[bn + 3][kb]);
    }
    __syncthreads();
    short8 ah = *(const short8*)&Ah[w * 16 + l16][lq * 8];
    short8 al = *(const short8*)&Al[w * 16 + l16][lq * 8];
    #pragma unroll
    for (int nt = 0; nt < 4; nt++){
      short8 bh = *(const short8*)&Bh[nt * 16 + l16][lq * 8];
      short8 bl = *(const short8*)&Bl[nt * 16 + l16][lq * 8];
      acc[nt] = __builtin_amdgcn_mfma_f32_16x16x32_bf16(ah, bh, acc[nt], 0, 0, 0);
      acc[nt] = __builtin_amdgcn_mfma_f32_16x16x32_bf16(ah, bl, acc[nt], 0, 0, 0);
      acc[nt] = __builtin_amdgcn_mfma_f32_16x16x32_bf16(al, bh, acc[nt], 0, 0, 0);
    }
    __syncthreads();
  }
  #pragma unroll
  for (int nt = 0; nt < 4; nt++)
    #pragma unroll
    for (int i = 0; i < 4; i++){
      int r = row0 + w * 16 + lq * 4 + i;
      if (r < me) G[(size_t)(off + r) * N + col0 + nt * 16 + l16] = acc[nt][i];
    }
}

// ---------------- expert down split-bf16 MFMA GEMM + weighted scatter-add ----------------
__global__ __launch_bounds__(256)
void k_mgemm_dn(const float* __restrict__ he, const float* __restrict__ edn_l,
                float* __restrict__ routed, const int* __restrict__ counts,
                const int* __restrict__ offsets, const int* __restrict__ rowtok,
                const float* __restrict__ roww){
  const int e = blockIdx.z;
  const int me = counts[e];
  const int row0 = blockIdx.y * 64;
  if (row0 >= me) return;
  const int off = offsets[e];
  const float* B = edn_l + (size_t)e * F_ * D_;
  const int N = D_, K = F_;
  __shared__ short Ah[64][40], Al[64][40];
  __shared__ short Bh[64][40], Bl[64][40];
  int tid = threadIdx.x;
  int col0 = blockIdx.x * 64;
  int w = tid >> 6, lane = tid & 63, l16 = lane & 15, lq = lane >> 4;
  f32x4 acc[4] = {};
  int ar = tid >> 3, ak = (tid & 7) * 4;
  int bk = tid >> 4, bn = (tid & 15) * 4;
  for (int k0 = 0; k0 < K; k0 += 32){
    #pragma unroll
    for (int rr = 0; rr < 64; rr += 32){
      int r = ar + rr;
      float4 av = (row0 + r < me) ? *(const float4*)(he + (size_t)(off + row0 + r) * F_ + k0 + ak)
                                  : make_float4(0.f, 0.f, 0.f, 0.f);
      split2(av.x, Ah[r][ak + 0], Al[r][ak + 0]);
      split2(av.y, Ah[r][ak + 1], Al[r][ak + 1]);
      split2(av.z, Ah[r][ak + 2], Al[r][ak + 2]);
      split2(av.w, Ah[r][ak + 3], Al[r][ak + 3]);
    }
    #pragma unroll
    for (int kk = 0; kk < 32; kk += 16){
      int kb = bk + kk;
      float4 bv = *(const float4*)(B + (size_t)(k0 + kb) * N + col0 + bn);
      split2(bv.x, Bh[bn + 0][kb], Bl[bn + 0][kb]);
      split2(bv.y, Bh[bn + 1][kb], Bl[bn + 1][kb]);
      split2(bv.z, Bh[bn + 2][kb], Bl[bn + 2][kb]);
      split2(bv.w, Bh[bn + 3][kb], Bl[bn + 3][kb]);
    }
    __syncthreads();
    short8 ah = *(const short8*)&Ah[w * 16 + l16][lq * 8];
    short8 al = *(const short8*)&Al[w * 16 + l16][lq * 8];
    #pragma unroll
    for (int nt = 0; nt < 4; nt++){
      short8 bh = *(const short8*)&Bh[nt * 16 + l16][lq * 8];
      short8 bl = *(const short8*)&Bl[nt * 16 + l16][lq * 8];
      acc[nt] = __builtin_amdgcn_mfma_f32_16x16x32_bf16(ah, bh, acc[nt], 0, 0, 0);
      acc[nt] = __builtin_amdgcn_mfma_f32_16x16x32_bf16(ah, bl, acc[nt], 0, 0, 0);
      acc[nt] = __builtin_amdgcn_mfma_f32_16x16x32_bf16(al, bh, acc[nt], 0, 0, 0);
    }
    __syncthreads();
  }
  #pragma unroll
  for (int i = 0; i < 4; i++){
    int r = row0 + w * 16 + lq * 4 + i;
    if (r < me){
      int tok = rowtok[off + r];
      float wgt = roww[off + r];
      float* cp = routed + (size_t)tok * D_ + col0;
      #pragma unroll
      for (int nt = 0; nt < 4; nt++)
        atomicAdd(&cp[nt * 16 + l16], wgt * acc[nt][i]);
    }
  }
}

// ---------------- SiLU(gate)*up ----------------
__global__ void k_silumul(const float* __restrict__ g, float* __restrict__ out,
                          int width, int half){
  int idx = blockIdx.x * 256 + threadIdx.x;
  int r = idx / half, f = idx - r * half;
  float a = g[(size_t)r * width + f];
  float b = g[(size_t)r * width + half + f];
  out[idx] = a * b / (1.f + __expf(-a));
}

// ---------------- shared-expert sigmoid gate ----------------
__global__ __launch_bounds__(256)
void k_gate(const float* __restrict__ hn, const float* __restrict__ sg,
            float* __restrict__ gate){
  int t = blockIdx.x, tid = threadIdx.x;
  const float* xr = hn + (size_t)t * D_;
  float s = 0.f;
  for (int d = tid; d < D_; d += 256) s += xr[d] * sg[d];
  #pragma unroll
  for (int o = 32; o; o >>= 1) s += __shfl_xor(s, o);
  __shared__ float red[4];
  if ((tid & 63) == 0) red[tid >> 6] = s;
  __syncthreads();
  if (tid == 0){
    float tot = red[0] + red[1] + red[2] + red[3];
    gate[t] = 1.f / (1.f + __expf(-tot));
  }
}

// ---------------- router: softmax + top-2 + renorm ----------------
__global__ __launch_bounds__(64)
void k_router(const float* __restrict__ hn, const float* __restrict__ rw,
              int* __restrict__ counts, int* __restrict__ top_e,
              float* __restrict__ top_w){
  int t = blockIdx.x;
  int lane = threadIdx.x;
  int e = lane & 7, c = lane >> 3;
  const float* xr = hn + (size_t)t * D_;
  float s = 0.f;
  for (int d = c * 128; d < c * 128 + 128; d++) s += xr[d] * rw[d * E_ + e];
  s += __shfl_down(s, 32);
  s += __shfl_down(s, 16);
  s += __shfl_down(s, 8);
  float v[8];
  #pragma unroll
  for (int qq = 0; qq < 8; qq++) v[qq] = __shfl(s, qq);
  if (lane == 0){
    float mx = v[0];
    #pragma unroll
    for (int qq = 1; qq < 8; qq++) mx = fmaxf(mx, v[qq]);
    float p[8];
    #pragma unroll
    for (int qq = 0; qq < 8; qq++) p[qq] = __expf(v[qq] - mx);
    int i0 = 0;
    #pragma unroll
    for (int qq = 1; qq < 8; qq++) if (p[qq] > p[i0]) i0 = qq;
    int i1 = (i0 == 0) ? 1 : 0;
    #pragma unroll
    for (int qq = 0; qq < 8; qq++) if (qq != i0 && p[qq] > p[i1]) i1 = qq;
    float w0 = p[i0], w1 = p[i1];
    float inv = 1.f / (w0 + w1);
    top_e[t * 2 + 0] = i0; top_w[t * 2 + 0] = w0 * inv;
    top_e[t * 2 + 1] = i1; top_w[t * 2 + 1] = w1 * inv;
    atomicAdd(&counts[i0], 1);
    atomicAdd(&counts[i1], 1);
  }
}

__global__ void k_prefix(const int* __restrict__ counts, int* __restrict__ offsets,
                         int* __restrict__ cursor){
  if (threadIdx.x == 0 && blockIdx.x == 0){
    int acc = 0;
    for (int e = 0; e < E_; e++){ offsets[e] = acc; cursor[e] = acc; acc += counts[e]; }
  }
}

__global__ void k_assign(const int* __restrict__ top_e, const float* __restrict__ top_w,
                         int* __restrict__ cursor, int* __restrict__ rowtok,
                         float* __restrict__ roww){
  int i = blockIdx.x * 256 + threadIdx.x;
  if (i >= T_ * TOPK_) return;
  int e = top_e[i];
  int slot = atomicAdd(&cursor[e], 1);
  rowtok[slot] = i >> 1;
  roww[slot] = top_w[i];
}

// ---------------- h = routed + shared * gate[t] ----------------
__global__ void k_combine(float* __restrict__ h, const float* __restrict__ routed,
                          const float* __restrict__ shexp, const float* __restrict__ gate){
  int idx = blockIdx.x * 256 + threadIdx.x;
  h[idx] = routed[idx] + shexp[idx] * gate[idx >> 10];
}

// ---------------- final: out = rms(res + h, final_ln), fp32 out ----------------
__global__ __launch_bounds__(256)
void k_final_rms(const float* __restrict__ resv, const float* __restrict__ hv,
                 const float* __restrict__ w, float* __restrict__ out){
  int t = blockIdx.x, tid = threadIdx.x;
  const float* xr = resv + (size_t)t * D_;
  const float* hr = hv + (size_t)t * D_;
  float ss = 0.f;
  for (int d = tid; d < D_; d += 256){ float v = xr[d] + hr[d]; ss += v * v; }
  #pragma unroll
  for (int o = 32; o; o >>= 1) ss += __shfl_xor(ss, o);
  __shared__ float red[4];
  if ((tid & 63) == 0) red[tid >> 6] = ss;
  __syncthreads();
  float r = rsqrtf((red[0] + red[1] + red[2] + red[3]) * (1.f / D_) + 1e-6f);
  float* orow = out + (size_t)t * D_;
  for (int d = tid; d < D_; d += 256) orow[d] = (xr[d] + hr[d]) * r * w[d];
}

extern "C" void kernel_launch(void* const* d_in, const int* in_sizes, int n_in,
                              void* d_out, int out_size, void* d_ws, size_t ws_size,
                              hipStream_t stream){
  (void)in_sizes; (void)n_in; (void)out_size; (void)ws_size;
  const int* ids = (const int*)d_in[0];
  const int* pos = (const int*)d_in[1];
  const float* emb = (const float*)d_in[2];
  const float* ln1 = (const float*)d_in[3];
  const float* wq  = (const float*)d_in[4];
  const float* wk  = (const float*)d_in[5];
  const float* wv  = (const float*)d_in[6];
  const float* wo  = (const float*)d_in[7];
  const float* qn  = (const float*)d_in[8];
  const float* kn  = (const float*)d_in[9];
  const float* ln2 = (const float*)d_in[10];
  const float* rw  = (const float*)d_in[11];
  const float* egu = (const float*)d_in[12];
  const float* edn = (const float*)d_in[13];
  const float* sgu = (const float*)d_in[14];
  const float* sdn = (const float*)d_in[15];
  const float* sg  = (const float*)d_in[16];
  const float* fln = (const float*)d_in[17];

  float* ws = (float*)d_ws;
  const size_t MB = (size_t)1 << 20;
  float* res    = ws;
  float* h      = ws + 1 * MB;
  float* hn     = ws + 2 * MB;
  float* qlin   = ws + 3 * MB;
  float* kbuf   = ws + 4 * MB;
  float* vbuf   = kbuf + T_ * KV_ * DH_;
  float* attnb  = ws + 5 * MB;
  float* gu     = ws + 6 * MB;
  float* sact   = ws + 10 * MB;
  float* shexp  = ws + 12 * MB;
  float* G      = ws + 13 * MB;
  float* he     = ws + 15 * MB;
  float* routed = ws + 16 * MB;
  float* gate   = ws + 17 * MB;
  float* roww   = gate + 4096;
  float* top_w  = roww + 4096;
  int* counts   = (int*)(top_w + 4096);
  int* offsets  = counts + 8;
  int* cursor   = offsets + 8;
  int* top_e    = cursor + 8;
  int* rowtok   = top_e + 2048;

  const int NTD = T_ * D_ / 256;

  k_embed<<<NTD, 256, 0, stream>>>(ids, emb, h, res);

  for (int i = 0; i < L_; i++){
    // ---- attention ----
    k_add<<<NTD, 256, 0, stream>>>(res, h);
    k_rms<<<T_, 256, 0, stream>>>(res, ln1 + (size_t)i * D_, hn);
    k_mgemm<<<dim3(16, 16), 256, 0, stream>>>(hn, wq + (size_t)i * D_ * (H_ * DH_), qlin, T_, H_ * DH_, D_);
    k_mgemm<<<dim3(4, 16), 256, 0, stream>>>(hn, wk + (size_t)i * D_ * (KV_ * DH_), kbuf, T_, KV_ * DH_, D_);
    k_mgemm<<<dim3(4, 16), 256, 0, stream>>>(hn, wv + (size_t)i * D_ * (KV_ * DH_), vbuf, T_, KV_ * DH_, D_);
    k_qknorm_rope<<<T_ * H_, 64, 0, stream>>>(qlin, qn + (size_t)i * DH_, pos, H_);
    k_qknorm_rope<<<T_ * KV_, 64, 0, stream>>>(kbuf, kn + (size_t)i * DH_, pos, KV_);
    k_attn<<<dim3(H_, T_), 256, 0, stream>>>(qlin, kbuf, vbuf, attnb);
    k_mgemm<<<dim3(16, 16), 256, 0, stream>>>(attnb, wo + (size_t)i * (H_ * DH_) * D_, h, T_, D_, H_ * DH_);
    k_add<<<NTD, 256, 0, stream>>>(res, h);
    // ---- MoE MLP ----
    k_rms<<<T_, 256, 0, stream>>>(res, ln2 + (size_t)i * D_, hn);
    k_mgemm<<<dim3(64, 16), 256, 0, stream>>>(hn, sgu + (size_t)i * D_ * (2 * FS_), gu, T_, 2 * FS_, D_);
    k_silumul<<<T_ * FS_ / 256, 256, 0, stream>>>(gu, sact, 2 * FS_, FS_);
    k_mgemm<<<dim3(16, 16), 256, 0, stream>>>(sact, sdn + (size_t)i * FS_ * D_, shexp, T_, D_, FS_);
    k_gate<<<T_, 256, 0, stream>>>(hn, sg + (size_t)i * D_, gate);
    k_zero_i32<<<1, 64, 0, stream>>>(counts, 8);
    k_router<<<T_, 64, 0, stream>>>(hn, rw + (size_t)i * D_ * E_, counts, top_e, top_w);
    k_prefix<<<1, 1, 0, stream>>>(counts, offsets, cursor);
    k_assign<<<8, 256, 0, stream>>>(top_e, top_w, cursor, rowtok, roww);
    k_mgemm_up<<<dim3(16, 32, 8), 256, 0, stream>>>(hn, egu + (size_t)i * E_ * D_ * (2 * F_), G, counts, offsets, rowtok);
    k_silumul<<<T_ * TOPK_ * F_ / 256, 256, 0, stream>>>(G, he, 2 * F_, F_);
    k_zero_f32<<<NTD, 256, 0, stream>>>(routed);
    k_mgemm_dn<<<dim3(16, 32, 8), 256, 0, stream>>>(he, edn + (size_t)i * E_ * F_ * D_, routed, counts, offsets, rowtok, roww);
    k_combine<<<NTD, 256, 0, stream>>>(h, routed, shexp, gate);
  }

  k_final_rms<<<T_, 256, 0, stream>>>(res, h, fln, (float*)d_out);
}

// Round 6
// 1859.332 us; speedup vs baseline: 1.8091x; 1.3434x over previous
//
#include <hip/hip_runtime.h>
#include <hip/hip_bf16.h>

#define T_ 1024
#define D_ 1024
#define H_ 16
#define KV_ 4
#define DH_ 64
#define E_ 8
#define TOPK_ 2
#define F_ 512
#define FS_ 2048
#define L_ 2

typedef unsigned int uint32;
typedef __attribute__((ext_vector_type(8))) short short8;
typedef __attribute__((ext_vector_type(4))) float f32x4;

__device__ __forceinline__ short f2bf(float f){   // RNE fp32 -> bf16 bits
  uint32 u = __float_as_uint(f);
  return (short)((u + 0x7fffu + ((u >> 16) & 1u)) >> 16);
}
__device__ __forceinline__ float bf2f(short s){
  return __uint_as_float(((uint32)(unsigned short)s) << 16);
}
__device__ __forceinline__ void split2(float x, short& hi, short& lo){
  hi = f2bf(x);
  lo = f2bf(x - bf2f(hi));
}

// ---------------- embedding gather + zero residual ----------------
__global__ void k_embed(const int* __restrict__ ids, const float* __restrict__ emb,
                        float* __restrict__ h, float* __restrict__ res){
  int idx = blockIdx.x * 256 + threadIdx.x;
  int t = idx >> 10, d = idx & 1023;
  h[idx] = emb[(size_t)ids[t] * D_ + d];
  res[idx] = 0.f;
}

__global__ void k_zero_i32(int* __restrict__ p, int n){
  int i = blockIdx.x * 64 + threadIdx.x;
  if (i < n) p[i] = 0;
}

// ---------------- fused: res += h; out = rms(res) * w ----------------
__global__ __launch_bounds__(256)
void k_fused_rms(float* __restrict__ res, const float* __restrict__ h,
                 const float* __restrict__ w, float* __restrict__ out){
  int t = blockIdx.x, tid = threadIdx.x;
  float* rr = res + (size_t)t * D_;
  const float* hr = h + (size_t)t * D_;
  float ss = 0.f;
  float vloc[4];
  #pragma unroll
  for (int u = 0; u < 4; u++){
    int d = tid + u * 256;
    float v = rr[d] + hr[d];
    vloc[u] = v;
    ss += v * v;
  }
  #pragma unroll
  for (int o = 32; o; o >>= 1) ss += __shfl_xor(ss, o);
  __shared__ float red[4];
  if ((tid & 63) == 0) red[tid >> 6] = ss;
  __syncthreads();
  float r = rsqrtf((red[0] + red[1] + red[2] + red[3]) * (1.f / D_) + 1e-6f);
  float* orow = out + (size_t)t * D_;
  #pragma unroll
  for (int u = 0; u < 4; u++){
    int d = tid + u * 256;
    rr[d] = vloc[u];
    orow[d] = vloc[u] * r * w[d];
  }
}

// ---------------- per-head RMSNorm + RoPE (in place) ----------------
__global__ __launch_bounds__(64)
void k_qknorm_rope(float* __restrict__ buf, const float* __restrict__ nw,
                   const int* __restrict__ pos, int nheads){
  int row = blockIdx.x;
  int t = row / nheads;
  int lane = threadIdx.x;
  int base = row * DH_ + lane;
  float x = buf[base];
  float ss = x * x;
  #pragma unroll
  for (int o = 32; o; o >>= 1) ss += __shfl_xor(ss, o);
  float r = rsqrtf(ss * (1.f / DH_) + 1e-6f);
  float xn = x * r * nw[lane];
  int j = lane & 31;
  float inv = powf(1.0e6f, -(float)j * (1.f / 32.f));
  float ang = (float)pos[t] * inv;
  float s, c;
  sincosf(ang, &s, &c);
  float p = __shfl_xor(xn, 32);
  float rot = (lane < 32) ? -p : p;
  buf[base] = xn * c + rot * s;
}

// ---------------- flash attention: one block per (head, 64-query tile) ----------------
__global__ __launch_bounds__(256)
void k_fattn(const float* __restrict__ q, const float* __restrict__ k,
             const float* __restrict__ v, float* __restrict__ out){
  int h = blockIdx.x, qt = blockIdx.y;
  int kvh = h >> 2;
  int tid = threadIdx.x;
  int ri = tid >> 4, ci = tid & 15;       // rows ri*4..+3, keys/dims ci*4..+3
  __shared__ float qs[64][68];
  __shared__ float kv[64][68];            // K during QK phase, V during PV phase
  __shared__ float ps[64][68];
  {
    int r = tid >> 2, dseg = (tid & 3) * 16;
    const float* qp = q + ((size_t)(qt * 64 + r) * H_ + h) * DH_ + dseg;
    #pragma unroll
    for (int u = 0; u < 16; u += 4)
      *(float4*)&qs[r][dseg + u] = *(const float4*)(qp + u);
  }
  float m_i[4], l_i[4];
  f32x4 acc[4];
  #pragma unroll
  for (int i = 0; i < 4; i++){ m_i[i] = -1e30f; l_i[i] = 0.f; acc[i] = (f32x4){0.f,0.f,0.f,0.f}; }

  for (int kt = 0; kt <= qt; kt++){
    __syncthreads();                      // prev PV done (kv reuse); qs ready on iter 0
    {
      int r = tid >> 2, dseg = (tid & 3) * 16;
      const float* kp = k + ((size_t)(kt * 64 + r) * KV_ + kvh) * DH_ + dseg;
      #pragma unroll
      for (int u = 0; u < 16; u += 4)
        *(float4*)&kv[r][dseg + u] = *(const float4*)(kp + u);
    }
    __syncthreads();
    // ---- scores 4x4 micro-tile ----
    float s[4][4] = {};
    for (int d = 0; d < 64; d += 4){
      float4 qv[4], kvv[4];
      #pragma unroll
      for (int rr = 0; rr < 4; rr++) qv[rr] = *(float4*)&qs[ri * 4 + rr][d];
      #pragma unroll
      for (int cc = 0; cc < 4; cc++) kvv[cc] = *(float4*)&kv[ci * 4 + cc][d];
      #pragma unroll
      for (int rr = 0; rr < 4; rr++)
        #pragma unroll
        for (int cc = 0; cc < 4; cc++)
          s[rr][cc] += qv[rr].x * kvv[cc].x + qv[rr].y * kvv[cc].y
                     + qv[rr].z * kvv[cc].z + qv[rr].w * kvv[cc].w;
    }
    bool diag = (kt == qt);
    #pragma unroll
    for (int rr = 0; rr < 4; rr++){
      #pragma unroll
      for (int cc = 0; cc < 4; cc++){
        float sv = s[rr][cc] * 0.125f;
        if (diag && (ci * 4 + cc > ri * 4 + rr)) sv = -1e30f;
        s[rr][cc] = sv;
      }
    }
    // ---- online softmax (rowwise over 16 lanes ci) ----
    #pragma unroll
    for (int rr = 0; rr < 4; rr++){
      float mx = fmaxf(fmaxf(s[rr][0], s[rr][1]), fmaxf(s[rr][2], s[rr][3]));
      #pragma unroll
      for (int o = 8; o; o >>= 1) mx = fmaxf(mx, __shfl_xor(mx, o));
      float mn = fmaxf(m_i[rr], mx);
      float al = __expf(m_i[rr] - mn);
      float lsum = 0.f;
      #pragma unroll
      for (int cc = 0; cc < 4; cc++){
        float p = __expf(s[rr][cc] - mn);
        ps[ri * 4 + rr][ci * 4 + cc] = p;
        lsum += p;
      }
      #pragma unroll
      for (int o = 8; o; o >>= 1) lsum += __shfl_xor(lsum, o);
      l_i[rr] = l_i[rr] * al + lsum;
      m_i[rr] = mn;
      acc[rr] *= al;
    }
    __syncthreads();                      // QK done reading kv; ps visible
    {
      int r = tid >> 2, dseg = (tid & 3) * 16;
      const float* vp = v + ((size_t)(kt * 64 + r) * KV_ + kvh) * DH_ + dseg;
      #pragma unroll
      for (int u = 0; u < 16; u += 4)
        *(float4*)&kv[r][dseg + u] = *(const float4*)(vp + u);
    }
    __syncthreads();
    // ---- PV: dims ci*4..+3 ----
    for (int j = 0; j < 64; j += 4){
      float4 pv[4];
      #pragma unroll
      for (int rr = 0; rr < 4; rr++) pv[rr] = *(float4*)&ps[ri * 4 + rr][j];
      #pragma unroll
      for (int jj = 0; jj < 4; jj++){
        float4 vv = *(float4*)&kv[j + jj][ci * 4];
        f32x4 vf = {vv.x, vv.y, vv.z, vv.w};
        #pragma unroll
        for (int rr = 0; rr < 4; rr++)
          acc[rr] += (&pv[rr].x)[jj] * vf;
      }
    }
  }
  #pragma unroll
  for (int rr = 0; rr < 4; rr++){
    float inv = 1.f / l_i[rr];
    float4 o;
    o.x = acc[rr][0] * inv; o.y = acc[rr][1] * inv;
    o.z = acc[rr][2] * inv; o.w = acc[rr][3] * inv;
    *(float4*)(out + (size_t)(qt * 64 + ri * 4 + rr) * (H_ * DH_) + h * DH_ + ci * 4) = o;
  }
}

// ---------------- split-bf16 MFMA GEMM: C = A @ B, ~fp32 accuracy ----------------
__global__ __launch_bounds__(256)
void k_mgemm(const float* __restrict__ A, const float* __restrict__ B,
             float* __restrict__ C, int M, int N, int K){
  __shared__ short Ah[64][40], Al[64][40];
  __shared__ short Bh[64][40], Bl[64][40];
  int tid = threadIdx.x;
  int row0 = blockIdx.y * 64, col0 = blockIdx.x * 64;
  int w = tid >> 6, lane = tid & 63, l16 = lane & 15, lq = lane >> 4;
  f32x4 acc[4] = {};
  int ar = tid >> 3, ak = (tid & 7) * 4;
  int bk = tid >> 4, bn = (tid & 15) * 4;
  for (int k0 = 0; k0 < K; k0 += 32){
    #pragma unroll
    for (int rr = 0; rr < 64; rr += 32){
      int r = ar + rr, grow = row0 + r;
      float4 av = (grow < M) ? *(const float4*)(A + (size_t)grow * K + k0 + ak)
                             : make_float4(0.f, 0.f, 0.f, 0.f);
      split2(av.x, Ah[r][ak + 0], Al[r][ak + 0]);
      split2(av.y, Ah[r][ak + 1], Al[r][ak + 1]);
      split2(av.z, Ah[r][ak + 2], Al[r][ak + 2]);
      split2(av.w, Ah[r][ak + 3], Al[r][ak + 3]);
    }
    #pragma unroll
    for (int kk = 0; kk < 32; kk += 16){
      int kb = bk + kk;
      float4 bv = *(const float4*)(B + (size_t)(k0 + kb) * N + col0 + bn);
      split2(bv.x, Bh[bn + 0][kb], Bl[bn + 0][kb]);
      split2(bv.y, Bh[bn + 1][kb], Bl[bn + 1][kb]);
      split2(bv.z, Bh[bn + 2][kb], Bl[bn + 2][kb]);
      split2(bv.w, Bh[bn + 3][kb], Bl[bn + 3][kb]);
    }
    __syncthreads();
    short8 ah = *(const short8*)&Ah[w * 16 + l16][lq * 8];
    short8 al = *(const short8*)&Al[w * 16 + l16][lq * 8];
    #pragma unroll
    for (int nt = 0; nt < 4; nt++){
      short8 bh = *(const short8*)&Bh[nt * 16 + l16][lq * 8];
      short8 bl = *(const short8*)&Bl[nt * 16 + l16][lq * 8];
      acc[nt] = __builtin_amdgcn_mfma_f32_16x16x32_bf16(ah, bh, acc[nt], 0, 0, 0);
      acc[nt] = __builtin_amdgcn_mfma_f32_16x16x32_bf16(ah, bl, acc[nt], 0, 0, 0);
      acc[nt] = __builtin_amdgcn_mfma_f32_16x16x32_bf16(al, bh, acc[nt], 0, 0, 0);
    }
    __syncthreads();
  }
  #pragma unroll
  for (int nt = 0; nt < 4; nt++)
    #pragma unroll
    for (int i = 0; i < 4; i++){
      int r = row0 + w * 16 + lq * 4 + i;
      if (r < M) C[(size_t)r * N + col0 + nt * 16 + l16] = acc[nt][i];
    }
}

// ---------------- expert up split-bf16 MFMA GEMM (gathered A rows) ----------------
__global__ __launch_bounds__(256)
void k_mgemm_up(const float* __restrict__ hn, const float* __restrict__ egu_l,
                float* __restrict__ G, const int* __restrict__ counts,
                const int* __restrict__ offsets, const int* __restrict__ rowtok){
  const int e = blockIdx.z;
  const int me = counts[e];
  const int row0 = blockIdx.y * 64;
  if (row0 >= me) return;
  const int off = offsets[e];
  const float* B = egu_l + (size_t)e * D_ * (2 * F_);
  const int N = 2 * F_, K = D_;
  __shared__ short Ah[64][40], Al[64][40];
  __shared__ short Bh[64][40], Bl[64][40];
  int tid = threadIdx.x;
  int col0 = blockIdx.x * 64;
  int w = tid >> 6, lane = tid & 63, l16 = lane & 15, lq = lane >> 4;
  f32x4 acc[4] = {};
  int ar = tid >> 3, ak = (tid & 7) * 4;
  int bk = tid >> 4, bn = (tid & 15) * 4;
  int tok0 = (row0 + ar      < me) ? rowtok[off + row0 + ar]      : -1;
  int tok1 = (row0 + ar + 32 < me) ? rowtok[off + row0 + ar + 32] : -1;
  for (int k0 = 0; k0 < K; k0 += 32){
    {
      float4 av = (tok0 >= 0) ? *(const float4*)(hn + (size_t)tok0 * D_ + k0 + ak)
                              : make_float4(0.f, 0.f, 0.f, 0.f);
      split2(av.x, Ah[ar][ak + 0], Al[ar][ak + 0]);
      split2(av.y, Ah[ar][ak + 1], Al[ar][ak + 1]);
      split2(av.z, Ah[ar][ak + 2], Al[ar][ak + 2]);
      split2(av.w, Ah[ar][ak + 3], Al[ar][ak + 3]);
      float4 aw = (tok1 >= 0) ? *(const float4*)(hn + (size_t)tok1 * D_ + k0 + ak)
                              : make_float4(0.f, 0.f, 0.f, 0.f);
      split2(aw.x, Ah[ar + 32][ak + 0], Al[ar + 32][ak + 0]);
      split2(aw.y, Ah[ar + 32][ak + 1], Al[ar + 32][ak + 1]);
      split2(aw.z, Ah[ar + 32][ak + 2], Al[ar + 32][ak + 2]);
      split2(aw.w, Ah[ar + 32][ak + 3], Al[ar + 32][ak + 3]);
    }
    #pragma unroll
    for (int kk = 0; kk < 32; kk += 16){
      int kb = bk + kk;
      float4 bv = *(const float4*)(B + (size_t)(k0 + kb) * N + col0 + bn);
      split2(bv.x, Bh[bn + 0][kb], Bl[bn + 0][kb]);
      split2(bv.y, Bh[bn + 1][kb], Bl[bn + 1][kb]);
      split2(bv.z, Bh[bn + 2][kb], Bl[bn + 2][kb]);
      split2(bv.w, Bh[bn + 3][kb], Bl[bn + 3][kb]);
    }
    __syncthreads();
    short8 ah = *(const short8*)&Ah[w * 16 + l16][lq * 8];
    short8 al = *(const short8*)&Al[w * 16 + l16][lq * 8];
    #pragma unroll
    for (int nt = 0; nt < 4; nt++){
      short8 bh = *(const short8*)&Bh[nt * 16 + l16][lq * 8];
      short8 bl = *(const short8*)&Bl[nt * 16 + l16][lq * 8];
      acc[nt] = __builtin_amdgcn_mfma_f32_16x16x32_bf16(ah, bh, acc[nt], 0, 0, 0);
      acc[nt] = __builtin_amdgcn_mfma_f32_16x16x32_bf16(ah, bl, acc[nt], 0, 0, 0);
      acc[nt] = __builtin_amdgcn_mfma_f32_16x16x32_bf16(al, bh, acc[nt], 0, 0, 0);
    }
    __syncthreads();
  }
  #pragma unroll
  for (int nt = 0; nt < 4; nt++)
    #pragma unroll
    for (int i = 0; i < 4; i++){
      int r = row0 + w * 16 + lq * 4 + i;
      if (r < me) G[(size_t)(off + r) * N + col0 + nt * 16 + l16] = acc[nt][i];
    }
}

// ---------------- expert down split-bf16 MFMA GEMM + weighted scatter-add ----------------
__global__ __launch_bounds__(256)
void k_mgemm_dn(const float* __restrict__ he, const float* __restrict__ edn_l,
                float* __restrict__ routed, const int* __restrict__ counts,
                const int* __restrict__ offsets, const int* __restrict__ rowtok,
                const float* __restrict__ roww){
  const int e = blockIdx.z;
  const int me = counts[e];
  const int row0 = blockIdx.y * 64;
  if (row0 >= me) return;
  const int off = offsets[e];
  const float* B = edn_l + (size_t)e * F_ * D_;
  const int N = D_, K = F_;
  __shared__ short Ah[64][40], Al[64][40];
  __shared__ short Bh[64][40], Bl[64][40];
  int tid = threadIdx.x;
  int col0 = blockIdx.x * 64;
  int w = tid >> 6, lane = tid & 63, l16 = lane & 15, lq = lane >> 4;
  f32x4 acc[4] = {};
  int ar = tid >> 3, ak = (tid & 7) * 4;
  int bk = tid >> 4, bn = (tid & 15) * 4;
  for (int k0 = 0; k0 < K; k0 += 32){
    #pragma unroll
    for (int rr = 0; rr < 64; rr += 32){
      int r = ar + rr;
      float4 av = (row0 + r < me) ? *(const float4*)(he + (size_t)(off + row0 + r) * F_ + k0 + ak)
                                  : make_float4(0.f, 0.f, 0.f, 0.f);
      split2(av.x, Ah[r][ak + 0], Al[r][ak + 0]);
      split2(av.y, Ah[r][ak + 1], Al[r][ak + 1]);
      split2(av.z, Ah[r][ak + 2], Al[r][ak + 2]);
      split2(av.w, Ah[r][ak + 3], Al[r][ak + 3]);
    }
    #pragma unroll
    for (int kk = 0; kk < 32; kk += 16){
      int kb = bk + kk;
      float4 bv = *(const float4*)(B + (size_t)(k0 + kb) * N + col0 + bn);
      split2(bv.x, Bh[bn + 0][kb], Bl[bn + 0][kb]);
      split2(bv.y, Bh[bn + 1][kb], Bl[bn + 1][kb]);
      split2(bv.z, Bh[bn + 2][kb], Bl[bn + 2][kb]);
      split2(bv.w, Bh[bn + 3][kb], Bl[bn + 3][kb]);
    }
    __syncthreads();
    short8 ah = *(const short8*)&Ah[w * 16 + l16][lq * 8];
    short8 al = *(const short8*)&Al[w * 16 + l16][lq * 8];
    #pragma unroll
    for (int nt = 0; nt < 4; nt++){
      short8 bh = *(const short8*)&Bh[nt * 16 + l16][lq * 8];
      short8 bl = *(const short8*)&Bl[nt * 16 + l16][lq * 8];
      acc[nt] = __builtin_amdgcn_mfma_f32_16x16x32_bf16(ah, bh, acc[nt], 0, 0, 0);
      acc[nt] = __builtin_amdgcn_mfma_f32_16x16x32_bf16(ah, bl, acc[nt], 0, 0, 0);
      acc[nt] = __builtin_amdgcn_mfma_f32_16x16x32_bf16(al, bh, acc[nt], 0, 0, 0);
    }
    __syncthreads();
  }
  #pragma unroll
  for (int i = 0; i < 4; i++){
    int r = row0 + w * 16 + lq * 4 + i;
    if (r < me){
      int tok = rowtok[off + r];
      float wgt = roww[off + r];
      float* cp = routed + (size_t)tok * D_ + col0;
      #pragma unroll
      for (int nt = 0; nt < 4; nt++)
        atomicAdd(&cp[nt * 16 + l16], wgt * acc[nt][i]);
    }
  }
}

// ---------------- SiLU(gate)*up ----------------
__global__ void k_silumul(const float* __restrict__ g, float* __restrict__ out,
                          int width, int half){
  int idx = blockIdx.x * 256 + threadIdx.x;
  int r = idx / half, f = idx - r * half;
  float a = g[(size_t)r * width + f];
  float b = g[(size_t)r * width + half + f];
  out[idx] = a * b / (1.f + __expf(-a));
}

// ---------------- shared-expert sigmoid gate ----------------
__global__ __launch_bounds__(256)
void k_gate(const float* __restrict__ hn, const float* __restrict__ sg,
            float* __restrict__ gate){
  int t = blockIdx.x, tid = threadIdx.x;
  const float* xr = hn + (size_t)t * D_;
  float s = 0.f;
  for (int d = tid; d < D_; d += 256) s += xr[d] * sg[d];
  #pragma unroll
  for (int o = 32; o; o >>= 1) s += __shfl_xor(s, o);
  __shared__ float red[4];
  if ((tid & 63) == 0) red[tid >> 6] = s;
  __syncthreads();
  if (tid == 0){
    float tot = red[0] + red[1] + red[2] + red[3];
    gate[t] = 1.f / (1.f + __expf(-tot));
  }
}

// ---------------- router: softmax + top-2 + renorm ----------------
__global__ __launch_bounds__(64)
void k_router(const float* __restrict__ hn, const float* __restrict__ rw,
              int* __restrict__ counts, int* __restrict__ top_e,
              float* __restrict__ top_w){
  int t = blockIdx.x;
  int lane = threadIdx.x;
  int e = lane & 7, c = lane >> 3;
  const float* xr = hn + (size_t)t * D_;
  float s = 0.f;
  for (int d = c * 128; d < c * 128 + 128; d++) s += xr[d] * rw[d * E_ + e];
  s += __shfl_down(s, 32);
  s += __shfl_down(s, 16);
  s += __shfl_down(s, 8);
  float v[8];
  #pragma unroll
  for (int qq = 0; qq < 8; qq++) v[qq] = __shfl(s, qq);
  if (lane == 0){
    float mx = v[0];
    #pragma unroll
    for (int qq = 1; qq < 8; qq++) mx = fmaxf(mx, v[qq]);
    float p[8];
    #pragma unroll
    for (int qq = 0; qq < 8; qq++) p[qq] = __expf(v[qq] - mx);
    int i0 = 0;
    #pragma unroll
    for (int qq = 1; qq < 8; qq++) if (p[qq] > p[i0]) i0 = qq;
    int i1 = (i0 == 0) ? 1 : 0;
    #pragma unroll
    for (int qq = 0; qq < 8; qq++) if (qq != i0 && p[qq] > p[i1]) i1 = qq;
    float w0 = p[i0], w1 = p[i1];
    float inv = 1.f / (w0 + w1);
    top_e[t * 2 + 0] = i0; top_w[t * 2 + 0] = w0 * inv;
    top_e[t * 2 + 1] = i1; top_w[t * 2 + 1] = w1 * inv;
    atomicAdd(&counts[i0], 1);
    atomicAdd(&counts[i1], 1);
  }
}

__global__ void k_prefix(const int* __restrict__ counts, int* __restrict__ offsets,
                         int* __restrict__ cursor){
  if (threadIdx.x == 0 && blockIdx.x == 0){
    int acc = 0;
    for (int e = 0; e < E_; e++){ offsets[e] = acc; cursor[e] = acc; acc += counts[e]; }
  }
}

__global__ void k_assign(const int* __restrict__ top_e, const float* __restrict__ top_w,
                         int* __restrict__ cursor, int* __restrict__ rowtok,
                         float* __restrict__ roww){
  int i = blockIdx.x * 256 + threadIdx.x;
  if (i >= T_ * TOPK_) return;
  int e = top_e[i];
  int slot = atomicAdd(&cursor[e], 1);
  rowtok[slot] = i >> 1;
  roww[slot] = top_w[i];
}

// ---------------- h = shared * gate[t]  (experts scatter-add on top) ----------------
__global__ void k_prefill(float* __restrict__ h, const float* __restrict__ shexp,
                          const float* __restrict__ gate){
  int idx = blockIdx.x * 256 + threadIdx.x;
  h[idx] = shexp[idx] * gate[idx >> 10];
}

// ---------------- final: out = rms(res + h, final_ln), fp32 out ----------------
__global__ __launch_bounds__(256)
void k_final_rms(const float* __restrict__ resv, const float* __restrict__ hv,
                 const float* __restrict__ w, float* __restrict__ out){
  int t = blockIdx.x, tid = threadIdx.x;
  const float* xr = resv + (size_t)t * D_;
  const float* hr = hv + (size_t)t * D_;
  float ss = 0.f;
  for (int d = tid; d < D_; d += 256){ float v = xr[d] + hr[d]; ss += v * v; }
  #pragma unroll
  for (int o = 32; o; o >>= 1) ss += __shfl_xor(ss, o);
  __shared__ float red[4];
  if ((tid & 63) == 0) red[tid >> 6] = ss;
  __syncthreads();
  float r = rsqrtf((red[0] + red[1] + red[2] + red[3]) * (1.f / D_) + 1e-6f);
  float* orow = out + (size_t)t * D_;
  for (int d = tid; d < D_; d += 256) orow[d] = (xr[d] + hr[d]) * r * w[d];
}

extern "C" void kernel_launch(void* const* d_in, const int* in_sizes, int n_in,
                              void* d_out, int out_size, void* d_ws, size_t ws_size,
                              hipStream_t stream){
  (void)in_sizes; (void)n_in; (void)out_size; (void)ws_size;
  const int* ids = (const int*)d_in[0];
  const int* pos = (const int*)d_in[1];
  const float* emb = (const float*)d_in[2];
  const float* ln1 = (const float*)d_in[3];
  const float* wq  = (const float*)d_in[4];
  const float* wk  = (const float*)d_in[5];
  const float* wv  = (const float*)d_in[6];
  const float* wo  = (const float*)d_in[7];
  const float* qn  = (const float*)d_in[8];
  const float* kn  = (const float*)d_in[9];
  const float* ln2 = (const float*)d_in[10];
  const float* rw  = (const float*)d_in[11];
  const float* egu = (const float*)d_in[12];
  const float* edn = (const float*)d_in[13];
  const float* sgu = (const float*)d_in[14];
  const float* sdn = (const float*)d_in[15];
  const float* sg  = (const float*)d_in[16];
  const float* fln = (const float*)d_in[17];

  float* ws = (float*)d_ws;
  const size_t MB = (size_t)1 << 20;
  float* res    = ws;
  float* h      = ws + 1 * MB;
  float* hn     = ws + 2 * MB;
  float* qlin   = ws + 3 * MB;
  float* kbuf   = ws + 4 * MB;
  float* vbuf   = kbuf + T_ * KV_ * DH_;
  float* attnb  = ws + 5 * MB;
  float* gu     = ws + 6 * MB;
  float* sact   = ws + 10 * MB;
  float* shexp  = ws + 12 * MB;
  float* G      = ws + 13 * MB;
  float* he     = ws + 15 * MB;
  float* gate   = ws + 17 * MB;
  float* roww   = gate + 4096;
  float* top_w  = roww + 4096;
  int* counts   = (int*)(top_w + 4096);
  int* offsets  = counts + 8;
  int* cursor   = offsets + 8;
  int* top_e    = cursor + 8;
  int* rowtok   = top_e + 2048;

  const int NTD = T_ * D_ / 256;

  k_embed<<<NTD, 256, 0, stream>>>(ids, emb, h, res);

  for (int i = 0; i < L_; i++){
    // ---- attention ----
    k_fused_rms<<<T_, 256, 0, stream>>>(res, h, ln1 + (size_t)i * D_, hn);
    k_mgemm<<<dim3(16, 16), 256, 0, stream>>>(hn, wq + (size_t)i * D_ * (H_ * DH_), qlin, T_, H_ * DH_, D_);
    k_mgemm<<<dim3(4, 16), 256, 0, stream>>>(hn, wk + (size_t)i * D_ * (KV_ * DH_), kbuf, T_, KV_ * DH_, D_);
    k_mgemm<<<dim3(4, 16), 256, 0, stream>>>(hn, wv + (size_t)i * D_ * (KV_ * DH_), vbuf, T_, KV_ * DH_, D_);
    k_qknorm_rope<<<T_ * H_, 64, 0, stream>>>(qlin, qn + (size_t)i * DH_, pos, H_);
    k_qknorm_rope<<<T_ * KV_, 64, 0, stream>>>(kbuf, kn + (size_t)i * DH_, pos, KV_);
    k_fattn<<<dim3(H_, T_ / 64), 256, 0, stream>>>(qlin, kbuf, vbuf, attnb);
    k_mgemm<<<dim3(16, 16), 256, 0, stream>>>(attnb, wo + (size_t)i * (H_ * DH_) * D_, h, T_, D_, H_ * DH_);
    // ---- MoE MLP ----
    k_fused_rms<<<T_, 256, 0, stream>>>(res, h, ln2 + (size_t)i * D_, hn);
    k_mgemm<<<dim3(64, 16), 256, 0, stream>>>(hn, sgu + (size_t)i * D_ * (2 * FS_), gu, T_, 2 * FS_, D_);
    k_silumul<<<T_ * FS_ / 256, 256, 0, stream>>>(gu, sact, 2 * FS_, FS_);
    k_mgemm<<<dim3(16, 16), 256, 0, stream>>>(sact, sdn + (size_t)i * FS_ * D_, shexp, T_, D_, FS_);
    k_gate<<<T_, 256, 0, stream>>>(hn, sg + (size_t)i * D_, gate);
    k_zero_i32<<<1, 64, 0, stream>>>(counts, 8);
    k_router<<<T_, 64, 0, stream>>>(hn, rw + (size_t)i * D_ * E_, counts, top_e, top_w);
    k_prefix<<<1, 1, 0, stream>>>(counts, offsets, cursor);
    k_assign<<<8, 256, 0, stream>>>(top_e, top_w, cursor, rowtok, roww);
    k_mgemm_up<<<dim3(16, 32, 8), 256, 0, stream>>>(hn, egu + (size_t)i * E_ * D_ * (2 * F_), G, counts, offsets, rowtok);
    k_silumul<<<T_ * TOPK_ * F_ / 256, 256, 0, stream>>>(G, he, 2 * F_, F_);
    k_prefill<<<NTD, 256, 0, stream>>>(h, shexp, gate);
    k_mgemm_dn<<<dim3(16, 32, 8), 256, 0, stream>>>(he, edn + (size_t)i * E_ * F_ * D_, h, counts, offsets, rowtok, roww);
  }

  k_final_rms<<<T_, 256, 0, stream>>>(res, h, fln, (float*)d_out);
}

// Round 7
// 1265.684 us; speedup vs baseline: 2.6576x; 1.4690x over previous
//
#include <hip/hip_runtime.h>
#include <hip/hip_bf16.h>

#define T_ 1024
#define D_ 1024
#define H_ 16
#define KV_ 4
#define DH_ 64
#define E_ 8
#define TOPK_ 2
#define F_ 512
#define FS_ 2048
#define L_ 2

typedef unsigned int uint32;
typedef __attribute__((ext_vector_type(8))) short short8;
typedef __attribute__((ext_vector_type(4))) float f32x4;

__device__ __forceinline__ short f2bf(float f){   // RNE fp32 -> bf16 bits
  uint32 u = __float_as_uint(f);
  return (short)((u + 0x7fffu + ((u >> 16) & 1u)) >> 16);
}
__device__ __forceinline__ float bf2f(short s){
  return __uint_as_float(((uint32)(unsigned short)s) << 16);
}

// ---------------- embedding gather + zero residual ----------------
__global__ void k_embed(const int* __restrict__ ids, const float* __restrict__ emb,
                        float* __restrict__ h, float* __restrict__ res){
  int idx = blockIdx.x * 256 + threadIdx.x;
  int t = idx >> 10, d = idx & 1023;
  h[idx] = emb[(size_t)ids[t] * D_ + d];
  res[idx] = 0.f;
}

__global__ void k_zero_i32(int* __restrict__ p, int n){
  int i = blockIdx.x * 64 + threadIdx.x;
  if (i < n) p[i] = 0;
}

// ---------------- fused: res += h; out = rms(res) * w ----------------
__global__ __launch_bounds__(256)
void k_fused_rms(float* __restrict__ res, const float* __restrict__ h,
                 const float* __restrict__ w, float* __restrict__ out){
  int t = blockIdx.x, tid = threadIdx.x;
  float* rr = res + (size_t)t * D_;
  const float* hr = h + (size_t)t * D_;
  float ss = 0.f;
  float vloc[4];
  #pragma unroll
  for (int u = 0; u < 4; u++){
    int d = tid + u * 256;
    float v = rr[d] + hr[d];
    vloc[u] = v;
    ss += v * v;
  }
  #pragma unroll
  for (int o = 32; o; o >>= 1) ss += __shfl_xor(ss, o);
  __shared__ float red[4];
  if ((tid & 63) == 0) red[tid >> 6] = ss;
  __syncthreads();
  float r = rsqrtf((red[0] + red[1] + red[2] + red[3]) * (1.f / D_) + 1e-6f);
  float* orow = out + (size_t)t * D_;
  #pragma unroll
  for (int u = 0; u < 4; u++){
    int d = tid + u * 256;
    rr[d] = vloc[u];
    orow[d] = vloc[u] * r * w[d];
  }
}

// ---------------- per-head RMSNorm + RoPE (in place) ----------------
__global__ __launch_bounds__(64)
void k_qknorm_rope(float* __restrict__ buf, const float* __restrict__ nw,
                   const int* __restrict__ pos, int nheads){
  int row = blockIdx.x;
  int t = row / nheads;
  int lane = threadIdx.x;
  int base = row * DH_ + lane;
  float x = buf[base];
  float ss = x * x;
  #pragma unroll
  for (int o = 32; o; o >>= 1) ss += __shfl_xor(ss, o);
  float r = rsqrtf(ss * (1.f / DH_) + 1e-6f);
  float xn = x * r * nw[lane];
  int j = lane & 31;
  float inv = powf(1.0e6f, -(float)j * (1.f / 32.f));
  float ang = (float)pos[t] * inv;
  float s, c;
  sincosf(ang, &s, &c);
  float p = __shfl_xor(xn, 32);
  float rot = (lane < 32) ? -p : p;
  buf[base] = xn * c + rot * s;
}

// ---------------- flash attention: one block per (head, 64-query tile) ----------------
__global__ __launch_bounds__(256)
void k_fattn(const float* __restrict__ q, const float* __restrict__ k,
             const float* __restrict__ v, float* __restrict__ out){
  int h = blockIdx.x, qt = blockIdx.y;
  int kvh = h >> 2;
  int tid = threadIdx.x;
  int ri = tid >> 4, ci = tid & 15;
  __shared__ float qs[64][68];
  __shared__ float kv[64][68];
  __shared__ float ps[64][68];
  {
    int r = tid >> 2, dseg = (tid & 3) * 16;
    const float* qp = q + ((size_t)(qt * 64 + r) * H_ + h) * DH_ + dseg;
    #pragma unroll
    for (int u = 0; u < 16; u += 4)
      *(float4*)&qs[r][dseg + u] = *(const float4*)(qp + u);
  }
  float m_i[4], l_i[4];
  f32x4 acc[4];
  #pragma unroll
  for (int i = 0; i < 4; i++){ m_i[i] = -1e30f; l_i[i] = 0.f; acc[i] = (f32x4){0.f,0.f,0.f,0.f}; }

  for (int kt = 0; kt <= qt; kt++){
    __syncthreads();
    {
      int r = tid >> 2, dseg = (tid & 3) * 16;
      const float* kp = k + ((size_t)(kt * 64 + r) * KV_ + kvh) * DH_ + dseg;
      #pragma unroll
      for (int u = 0; u < 16; u += 4)
        *(float4*)&kv[r][dseg + u] = *(const float4*)(kp + u);
    }
    __syncthreads();
    float s[4][4] = {};
    for (int d = 0; d < 64; d += 4){
      float4 qv[4], kvv[4];
      #pragma unroll
      for (int rr = 0; rr < 4; rr++) qv[rr] = *(float4*)&qs[ri * 4 + rr][d];
      #pragma unroll
      for (int cc = 0; cc < 4; cc++) kvv[cc] = *(float4*)&kv[ci * 4 + cc][d];
      #pragma unroll
      for (int rr = 0; rr < 4; rr++)
        #pragma unroll
        for (int cc = 0; cc < 4; cc++)
          s[rr][cc] += qv[rr].x * kvv[cc].x + qv[rr].y * kvv[cc].y
                     + qv[rr].z * kvv[cc].z + qv[rr].w * kvv[cc].w;
    }
    bool diag = (kt == qt);
    #pragma unroll
    for (int rr = 0; rr < 4; rr++){
      #pragma unroll
      for (int cc = 0; cc < 4; cc++){
        float sv = s[rr][cc] * 0.125f;
        if (diag && (ci * 4 + cc > ri * 4 + rr)) sv = -1e30f;
        s[rr][cc] = sv;
      }
    }
    #pragma unroll
    for (int rr = 0; rr < 4; rr++){
      float mx = fmaxf(fmaxf(s[rr][0], s[rr][1]), fmaxf(s[rr][2], s[rr][3]));
      #pragma unroll
      for (int o = 8; o; o >>= 1) mx = fmaxf(mx, __shfl_xor(mx, o));
      float mn = fmaxf(m_i[rr], mx);
      float al = __expf(m_i[rr] - mn);
      float lsum = 0.f;
      #pragma unroll
      for (int cc = 0; cc < 4; cc++){
        float p = __expf(s[rr][cc] - mn);
        ps[ri * 4 + rr][ci * 4 + cc] = p;
        lsum += p;
      }
      #pragma unroll
      for (int o = 8; o; o >>= 1) lsum += __shfl_xor(lsum, o);
      l_i[rr] = l_i[rr] * al + lsum;
      m_i[rr] = mn;
      acc[rr] *= al;
    }
    __syncthreads();
    {
      int r = tid >> 2, dseg = (tid & 3) * 16;
      const float* vp = v + ((size_t)(kt * 64 + r) * KV_ + kvh) * DH_ + dseg;
      #pragma unroll
      for (int u = 0; u < 16; u += 4)
        *(float4*)&kv[r][dseg + u] = *(const float4*)(vp + u);
    }
    __syncthreads();
    for (int j = 0; j < 64; j += 4){
      float4 pv[4];
      #pragma unroll
      for (int rr = 0; rr < 4; rr++) pv[rr] = *(float4*)&ps[ri * 4 + rr][j];
      #pragma unroll
      for (int jj = 0; jj < 4; jj++){
        float4 vv = *(float4*)&kv[j + jj][ci * 4];
        f32x4 vf = {vv.x, vv.y, vv.z, vv.w};
        #pragma unroll
        for (int rr = 0; rr < 4; rr++)
          acc[rr] += (&pv[rr].x)[jj] * vf;
      }
    }
  }
  #pragma unroll
  for (int rr = 0; rr < 4; rr++){
    float inv = 1.f / l_i[rr];
    float4 o;
    o.x = acc[rr][0] * inv; o.y = acc[rr][1] * inv;
    o.z = acc[rr][2] * inv; o.w = acc[rr][3] * inv;
    *(float4*)(out + (size_t)(qt * 64 + ri * 4 + rr) * (H_ * DH_) + h * DH_ + ci * 4) = o;
  }
}

// ======= split-bf16 MFMA GEMM core (vectored LDS staging + reg prefetch) =======
// LDS: [64][40] shorts, pitch 80 B (16B-aligned rows, <=2-way conflicts).
// Staging: thread owns row/col sm=tid&63, k-octet sk=(tid>>6)*8.
//   A: 2x float4 (contiguous k).  B: 8 k-strided dwords (256B coalesced/instr).
//   Writes: one ds_write_b128 hi + one lo each for A and B.

#define GEMM_LDS  __shared__ __align__(16) short Ah[64][40], Al[64][40], Bh[64][40], Bl[64][40]

__device__ __forceinline__ void split8(const float* src, short8& h8, short8& l8){
  #pragma unroll
  for (int j = 0; j < 8; j++){
    short hi = f2bf(src[j]);
    h8[j] = hi;
    l8[j] = f2bf(src[j] - bf2f(hi));
  }
}

// ---------------- generic: C[M,N] = A[M,K] @ B[K,N] ----------------
__global__ __launch_bounds__(256)
void k_mgemm(const float* __restrict__ A, const float* __restrict__ B,
             float* __restrict__ C, int M, int N, int K){
  GEMM_LDS;
  int tid = threadIdx.x;
  int row0 = blockIdx.y * 64, col0 = blockIdx.x * 64;
  int w = tid >> 6, lane = tid & 63, l16 = lane & 15, lq = lane >> 4;
  int sm = tid & 63, sk = (tid >> 6) * 8;
  bool aok = (row0 + sm) < M;
  const float* Arow = A + (size_t)(row0 + sm) * K + sk;
  const float* Bcol = B + (size_t)sk * N + col0 + sm;
  f32x4 acc[4] = {};
  float a_reg[8], b_reg[8];
  if (aok){
    *(float4*)&a_reg[0] = *(const float4*)(Arow);
    *(float4*)&a_reg[4] = *(const float4*)(Arow + 4);
  } else {
    #pragma unroll
    for (int j = 0; j < 8; j++) a_reg[j] = 0.f;
  }
  #pragma unroll
  for (int j = 0; j < 8; j++) b_reg[j] = Bcol[(size_t)j * N];
  int nc = K >> 5;
  for (int c = 0; c < nc; c++){
    short8 h8, l8;
    split8(a_reg, h8, l8);
    *(short8*)&Ah[sm][sk] = h8;
    *(short8*)&Al[sm][sk] = l8;
    split8(b_reg, h8, l8);
    *(short8*)&Bh[sm][sk] = h8;
    *(short8*)&Bl[sm][sk] = l8;
    __syncthreads();
    if (c + 1 < nc){
      const float* An = Arow + (c + 1) * 32;
      if (aok){
        *(float4*)&a_reg[0] = *(const float4*)(An);
        *(float4*)&a_reg[4] = *(const float4*)(An + 4);
      }
      const float* Bn = Bcol + (size_t)(c + 1) * 32 * N;
      #pragma unroll
      for (int j = 0; j < 8; j++) b_reg[j] = Bn[(size_t)j * N];
    }
    short8 ah = *(const short8*)&Ah[w * 16 + l16][lq * 8];
    short8 al = *(const short8*)&Al[w * 16 + l16][lq * 8];
    #pragma unroll
    for (int nt = 0; nt < 4; nt++){
      short8 bh = *(const short8*)&Bh[nt * 16 + l16][lq * 8];
      short8 bl = *(const short8*)&Bl[nt * 16 + l16][lq * 8];
      acc[nt] = __builtin_amdgcn_mfma_f32_16x16x32_bf16(ah, bh, acc[nt], 0, 0, 0);
      acc[nt] = __builtin_amdgcn_mfma_f32_16x16x32_bf16(ah, bl, acc[nt], 0, 0, 0);
      acc[nt] = __builtin_amdgcn_mfma_f32_16x16x32_bf16(al, bh, acc[nt], 0, 0, 0);
    }
    __syncthreads();
  }
  #pragma unroll
  for (int nt = 0; nt < 4; nt++)
    #pragma unroll
    for (int i = 0; i < 4; i++){
      int r = row0 + w * 16 + lq * 4 + i;
      if (r < M) C[(size_t)r * N + col0 + nt * 16 + l16] = acc[nt][i];
    }
}

// ---------------- expert up: gathered A rows ----------------
__global__ __launch_bounds__(256)
void k_mgemm_up(const float* __restrict__ hn, const float* __restrict__ egu_l,
                float* __restrict__ G, const int* __restrict__ counts,
                const int* __restrict__ offsets, const int* __restrict__ rowtok){
  const int e = blockIdx.z;
  const int me = counts[e];
  const int row0 = blockIdx.y * 64;
  if (row0 >= me) return;
  const int off = offsets[e];
  const float* B = egu_l + (size_t)e * D_ * (2 * F_);
  const int N = 2 * F_, K = D_;
  GEMM_LDS;
  int tid = threadIdx.x;
  int col0 = blockIdx.x * 64;
  int w = tid >> 6, lane = tid & 63, l16 = lane & 15, lq = lane >> 4;
  int sm = tid & 63, sk = (tid >> 6) * 8;
  bool aok = (row0 + sm) < me;
  int tok = aok ? rowtok[off + row0 + sm] : 0;
  const float* Arow = hn + (size_t)tok * K + sk;
  const float* Bcol = B + (size_t)sk * N + col0 + sm;
  f32x4 acc[4] = {};
  float a_reg[8], b_reg[8];
  if (aok){
    *(float4*)&a_reg[0] = *(const float4*)(Arow);
    *(float4*)&a_reg[4] = *(const float4*)(Arow + 4);
  } else {
    #pragma unroll
    for (int j = 0; j < 8; j++) a_reg[j] = 0.f;
  }
  #pragma unroll
  for (int j = 0; j < 8; j++) b_reg[j] = Bcol[(size_t)j * N];
  int nc = K >> 5;
  for (int c = 0; c < nc; c++){
    short8 h8, l8;
    split8(a_reg, h8, l8);
    *(short8*)&Ah[sm][sk] = h8;
    *(short8*)&Al[sm][sk] = l8;
    split8(b_reg, h8, l8);
    *(short8*)&Bh[sm][sk] = h8;
    *(short8*)&Bl[sm][sk] = l8;
    __syncthreads();
    if (c + 1 < nc){
      const float* An = Arow + (c + 1) * 32;
      if (aok){
        *(float4*)&a_reg[0] = *(const float4*)(An);
        *(float4*)&a_reg[4] = *(const float4*)(An + 4);
      }
      const float* Bn = Bcol + (size_t)(c + 1) * 32 * N;
      #pragma unroll
      for (int j = 0; j < 8; j++) b_reg[j] = Bn[(size_t)j * N];
    }
    short8 ah = *(const short8*)&Ah[w * 16 + l16][lq * 8];
    short8 al = *(const short8*)&Al[w * 16 + l16][lq * 8];
    #pragma unroll
    for (int nt = 0; nt < 4; nt++){
      short8 bh = *(const short8*)&Bh[nt * 16 + l16][lq * 8];
      short8 bl = *(const short8*)&Bl[nt * 16 + l16][lq * 8];
      acc[nt] = __builtin_amdgcn_mfma_f32_16x16x32_bf16(ah, bh, acc[nt], 0, 0, 0);
      acc[nt] = __builtin_amdgcn_mfma_f32_16x16x32_bf16(ah, bl, acc[nt], 0, 0, 0);
      acc[nt] = __builtin_amdgcn_mfma_f32_16x16x32_bf16(al, bh, acc[nt], 0, 0, 0);
    }
    __syncthreads();
  }
  #pragma unroll
  for (int nt = 0; nt < 4; nt++)
    #pragma unroll
    for (int i = 0; i < 4; i++){
      int r = row0 + w * 16 + lq * 4 + i;
      if (r < me) G[(size_t)(off + r) * N + col0 + nt * 16 + l16] = acc[nt][i];
    }
}

// ---------------- expert down: + weighted scatter-add ----------------
__global__ __launch_bounds__(256)
void k_mgemm_dn(const float* __restrict__ he, const float* __restrict__ edn_l,
                float* __restrict__ routed, const int* __restrict__ counts,
                const int* __restrict__ offsets, const int* __restrict__ rowtok,
                const float* __restrict__ roww){
  const int e = blockIdx.z;
  const int me = counts[e];
  const int row0 = blockIdx.y * 64;
  if (row0 >= me) return;
  const int off = offsets[e];
  const float* B = edn_l + (size_t)e * F_ * D_;
  const int N = D_, K = F_;
  GEMM_LDS;
  int tid = threadIdx.x;
  int col0 = blockIdx.x * 64;
  int w = tid >> 6, lane = tid & 63, l16 = lane & 15, lq = lane >> 4;
  int sm = tid & 63, sk = (tid >> 6) * 8;
  bool aok = (row0 + sm) < me;
  const float* Arow = he + (size_t)(off + row0 + (aok ? sm : 0)) * K + sk;
  const float* Bcol = B + (size_t)sk * N + col0 + sm;
  f32x4 acc[4] = {};
  float a_reg[8], b_reg[8];
  if (aok){
    *(float4*)&a_reg[0] = *(const float4*)(Arow);
    *(float4*)&a_reg[4] = *(const float4*)(Arow + 4);
  } else {
    #pragma unroll
    for (int j = 0; j < 8; j++) a_reg[j] = 0.f;
  }
  #pragma unroll
  for (int j = 0; j < 8; j++) b_reg[j] = Bcol[(size_t)j * N];
  int nc = K >> 5;
  for (int c = 0; c < nc; c++){
    short8 h8, l8;
    split8(a_reg, h8, l8);
    *(short8*)&Ah[sm][sk] = h8;
    *(short8*)&Al[sm][sk] = l8;
    split8(b_reg, h8, l8);
    *(short8*)&Bh[sm][sk] = h8;
    *(short8*)&Bl[sm][sk] = l8;
    __syncthreads();
    if (c + 1 < nc){
      const float* An = Arow + (c + 1) * 32;
      if (aok){
        *(float4*)&a_reg[0] = *(const float4*)(An);
        *(float4*)&a_reg[4] = *(const float4*)(An + 4);
      }
      const float* Bn = Bcol + (size_t)(c + 1) * 32 * N;
      #pragma unroll
      for (int j = 0; j < 8; j++) b_reg[j] = Bn[(size_t)j * N];
    }
    short8 ah = *(const short8*)&Ah[w * 16 + l16][lq * 8];
    short8 al = *(const short8*)&Al[w * 16 + l16][lq * 8];
    #pragma unroll
    for (int nt = 0; nt < 4; nt++){
      short8 bh = *(const short8*)&Bh[nt * 16 + l16][lq * 8];
      short8 bl = *(const short8*)&Bl[nt * 16 + l16][lq * 8];
      acc[nt] = __builtin_amdgcn_mfma_f32_16x16x32_bf16(ah, bh, acc[nt], 0, 0, 0);
      acc[nt] = __builtin_amdgcn_mfma_f32_16x16x32_bf16(ah, bl, acc[nt], 0, 0, 0);
      acc[nt] = __builtin_amdgcn_mfma_f32_16x16x32_bf16(al, bh, acc[nt], 0, 0, 0);
    }
    __syncthreads();
  }
  #pragma unroll
  for (int i = 0; i < 4; i++){
    int r = row0 + w * 16 + lq * 4 + i;
    if (r < me){
      int tok = rowtok[off + r];
      float wgt = roww[off + r];
      float* cp = routed + (size_t)tok * D_ + col0;
      #pragma unroll
      for (int nt = 0; nt < 4; nt++)
        atomicAdd(&cp[nt * 16 + l16], wgt * acc[nt][i]);
    }
  }
}

// ---------------- SiLU(gate)*up ----------------
__global__ void k_silumul(const float* __restrict__ g, float* __restrict__ out,
                          int width, int half){
  int idx = blockIdx.x * 256 + threadIdx.x;
  int r = idx / half, f = idx - r * half;
  float a = g[(size_t)r * width + f];
  float b = g[(size_t)r * width + half + f];
  out[idx] = a * b / (1.f + __expf(-a));
}

// ---------------- shared-expert sigmoid gate ----------------
__global__ __launch_bounds__(256)
void k_gate(const float* __restrict__ hn, const float* __restrict__ sg,
            float* __restrict__ gate){
  int t = blockIdx.x, tid = threadIdx.x;
  const float* xr = hn + (size_t)t * D_;
  float s = 0.f;
  for (int d = tid; d < D_; d += 256) s += xr[d] * sg[d];
  #pragma unroll
  for (int o = 32; o; o >>= 1) s += __shfl_xor(s, o);
  __shared__ float red[4];
  if ((tid & 63) == 0) red[tid >> 6] = s;
  __syncthreads();
  if (tid == 0){
    float tot = red[0] + red[1] + red[2] + red[3];
    gate[t] = 1.f / (1.f + __expf(-tot));
  }
}

// ---------------- router: softmax + top-2 + renorm ----------------
__global__ __launch_bounds__(64)
void k_router(const float* __restrict__ hn, const float* __restrict__ rw,
              int* __restrict__ counts, int* __restrict__ top_e,
              float* __restrict__ top_w){
  int t = blockIdx.x;
  int lane = threadIdx.x;
  int e = lane & 7, c = lane >> 3;
  const float* xr = hn + (size_t)t * D_;
  float s = 0.f;
  for (int d = c * 128; d < c * 128 + 128; d++) s += xr[d] * rw[d * E_ + e];
  s += __shfl_down(s, 32);
  s += __shfl_down(s, 16);
  s += __shfl_down(s, 8);
  float v[8];
  #pragma unroll
  for (int qq = 0; qq < 8; qq++) v[qq] = __shfl(s, qq);
  if (lane == 0){
    float mx = v[0];
    #pragma unroll
    for (int qq = 1; qq < 8; qq++) mx = fmaxf(mx, v[qq]);
    float p[8];
    #pragma unroll
    for (int qq = 0; qq < 8; qq++) p[qq] = __expf(v[qq] - mx);
    int i0 = 0;
    #pragma unroll
    for (int qq = 1; qq < 8; qq++) if (p[qq] > p[i0]) i0 = qq;
    int i1 = (i0 == 0) ? 1 : 0;
    #pragma unroll
    for (int qq = 0; qq < 8; qq++) if (qq != i0 && p[qq] > p[i1]) i1 = qq;
    float w0 = p[i0], w1 = p[i1];
    float inv = 1.f / (w0 + w1);
    top_e[t * 2 + 0] = i0; top_w[t * 2 + 0] = w0 * inv;
    top_e[t * 2 + 1] = i1; top_w[t * 2 + 1] = w1 * inv;
    atomicAdd(&counts[i0], 1);
    atomicAdd(&counts[i1], 1);
  }
}

__global__ void k_prefix(const int* __restrict__ counts, int* __restrict__ offsets,
                         int* __restrict__ cursor){
  if (threadIdx.x == 0 && blockIdx.x == 0){
    int acc = 0;
    for (int e = 0; e < E_; e++){ offsets[e] = acc; cursor[e] = acc; acc += counts[e]; }
  }
}

__global__ void k_assign(const int* __restrict__ top_e, const float* __restrict__ top_w,
                         int* __restrict__ cursor, int* __restrict__ rowtok,
                         float* __restrict__ roww){
  int i = blockIdx.x * 256 + threadIdx.x;
  if (i >= T_ * TOPK_) return;
  int e = top_e[i];
  int slot = atomicAdd(&cursor[e], 1);
  rowtok[slot] = i >> 1;
  roww[slot] = top_w[i];
}

// ---------------- h = shared * gate[t]  (experts scatter-add on top) ----------------
__global__ void k_prefill(float* __restrict__ h, const float* __restrict__ shexp,
                          const float* __restrict__ gate){
  int idx = blockIdx.x * 256 + threadIdx.x;
  h[idx] = shexp[idx] * gate[idx >> 10];
}

// ---------------- final: out = rms(res + h, final_ln), fp32 out ----------------
__global__ __launch_bounds__(256)
void k_final_rms(const float* __restrict__ resv, const float* __restrict__ hv,
                 const float* __restrict__ w, float* __restrict__ out){
  int t = blockIdx.x, tid = threadIdx.x;
  const float* xr = resv + (size_t)t * D_;
  const float* hr = hv + (size_t)t * D_;
  float ss = 0.f;
  for (int d = tid; d < D_; d += 256){ float v = xr[d] + hr[d]; ss += v * v; }
  #pragma unroll
  for (int o = 32; o; o >>= 1) ss += __shfl_xor(ss, o);
  __shared__ float red[4];
  if ((tid & 63) == 0) red[tid >> 6] = ss;
  __syncthreads();
  float r = rsqrtf((red[0] + red[1] + red[2] + red[3]) * (1.f / D_) + 1e-6f);
  float* orow = out + (size_t)t * D_;
  for (int d = tid; d < D_; d += 256) orow[d] = (xr[d] + hr[d]) * r * w[d];
}

extern "C" void kernel_launch(void* const* d_in, const int* in_sizes, int n_in,
                              void* d_out, int out_size, void* d_ws, size_t ws_size,
                              hipStream_t stream){
  (void)in_sizes; (void)n_in; (void)out_size; (void)ws_size;
  const int* ids = (const int*)d_in[0];
  const int* pos = (const int*)d_in[1];
  const float* emb = (const float*)d_in[2];
  const float* ln1 = (const float*)d_in[3];
  const float* wq  = (const float*)d_in[4];
  const float* wk  = (const float*)d_in[5];
  const float* wv  = (const float*)d_in[6];
  const float* wo  = (const float*)d_in[7];
  const float* qn  = (const float*)d_in[8];
  const float* kn  = (const float*)d_in[9];
  const float* ln2 = (const float*)d_in[10];
  const float* rw  = (const float*)d_in[11];
  const float* egu = (const float*)d_in[12];
  const float* edn = (const float*)d_in[13];
  const float* sgu = (const float*)d_in[14];
  const float* sdn = (const float*)d_in[15];
  const float* sg  = (const float*)d_in[16];
  const float* fln = (const float*)d_in[17];

  float* ws = (float*)d_ws;
  const size_t MB = (size_t)1 << 20;
  float* res    = ws;
  float* h      = ws + 1 * MB;
  float* hn     = ws + 2 * MB;
  float* qlin   = ws + 3 * MB;
  float* kbuf   = ws + 4 * MB;
  float* vbuf   = kbuf + T_ * KV_ * DH_;
  float* attnb  = ws + 5 * MB;
  float* gu     = ws + 6 * MB;
  float* sact   = ws + 10 * MB;
  float* shexp  = ws + 12 * MB;
  float* G      = ws + 13 * MB;
  float* he     = ws + 15 * MB;
  float* gate   = ws + 17 * MB;
  float* roww   = gate + 4096;
  float* top_w  = roww + 4096;
  int* counts   = (int*)(top_w + 4096);
  int* offsets  = counts + 8;
  int* cursor   = offsets + 8;
  int* top_e    = cursor + 8;
  int* rowtok   = top_e + 2048;

  const int NTD = T_ * D_ / 256;

  k_embed<<<NTD, 256, 0, stream>>>(ids, emb, h, res);

  for (int i = 0; i < L_; i++){
    // ---- attention ----
    k_fused_rms<<<T_, 256, 0, stream>>>(res, h, ln1 + (size_t)i * D_, hn);
    k_mgemm<<<dim3(16, 16), 256, 0, stream>>>(hn, wq + (size_t)i * D_ * (H_ * DH_), qlin, T_, H_ * DH_, D_);
    k_mgemm<<<dim3(4, 16), 256, 0, stream>>>(hn, wk + (size_t)i * D_ * (KV_ * DH_), kbuf, T_, KV_ * DH_, D_);
    k_mgemm<<<dim3(4, 16), 256, 0, stream>>>(hn, wv + (size_t)i * D_ * (KV_ * DH_), vbuf, T_, KV_ * DH_, D_);
    k_qknorm_rope<<<T_ * H_, 64, 0, stream>>>(qlin, qn + (size_t)i * DH_, pos, H_);
    k_qknorm_rope<<<T_ * KV_, 64, 0, stream>>>(kbuf, kn + (size_t)i * DH_, pos, KV_);
    k_fattn<<<dim3(H_, T_ / 64), 256, 0, stream>>>(qlin, kbuf, vbuf, attnb);
    k_mgemm<<<dim3(16, 16), 256, 0, stream>>>(attnb, wo + (size_t)i * (H_ * DH_) * D_, h, T_, D_, H_ * DH_);
    // ---- MoE MLP ----
    k_fused_rms<<<T_, 256, 0, stream>>>(res, h, ln2 + (size_t)i * D_, hn);
    k_mgemm<<<dim3(64, 16), 256, 0, stream>>>(hn, sgu + (size_t)i * D_ * (2 * FS_), gu, T_, 2 * FS_, D_);
    k_silumul<<<T_ * FS_ / 256, 256, 0, stream>>>(gu, sact, 2 * FS_, FS_);
    k_mgemm<<<dim3(16, 16), 256, 0, stream>>>(sact, sdn + (size_t)i * FS_ * D_, shexp, T_, D_, FS_);
    k_gate<<<T_, 256, 0, stream>>>(hn, sg + (size_t)i * D_, gate);
    k_zero_i32<<<1, 64, 0, stream>>>(counts, 8);
    k_router<<<T_, 64, 0, stream>>>(hn, rw + (size_t)i * D_ * E_, counts, top_e, top_w);
    k_prefix<<<1, 1, 0, stream>>>(counts, offsets, cursor);
    k_assign<<<8, 256, 0, stream>>>(top_e, top_w, cursor, rowtok, roww);
    k_mgemm_up<<<dim3(16, 32, 8), 256, 0, stream>>>(hn, egu + (size_t)i * E_ * D_ * (2 * F_), G, counts, offsets, rowtok);
    k_silumul<<<T_ * TOPK_ * F_ / 256, 256, 0, stream>>>(G, he, 2 * F_, F_);
    k_prefill<<<NTD, 256, 0, stream>>>(h, shexp, gate);
    k_mgemm_dn<<<dim3(16, 32, 8), 256, 0, stream>>>(he, edn + (size_t)i * E_ * F_ * D_, h, counts, offsets, rowtok, roww);
  }

  k_final_rms<<<T_, 256, 0, stream>>>(res, h, fln, (float*)d_out);
}